// Round 1
// baseline (2093.969 us; speedup 1.0000x reference)
//
#include <hip/hip_runtime.h>
#include <math.h>

#define MIN_NORM 1e-15f
#define MAXNORM  0.996f          /* (1 - 4e-3)/sqrt(c), c=1 */
#define ARTANH_CLIP 0.99999988f  /* float(1.0 - 1e-7) */

__device__ __forceinline__ float wave_sum(float v) {
#pragma unroll
    for (int off = 32; off > 0; off >>= 1) v += __shfl_xor(v, off, 64);
    return v;
}

__device__ __forceinline__ float artanh_c(float x) {
    x = fminf(fmaxf(x, -ARTANH_CLIP), ARTANH_CLIP);
    return 0.5f * (log1pf(x) - log1pf(-x));
}

__device__ __forceinline__ float tanh_c(float x) {
    return tanhf(fminf(fmaxf(x, -15.f), 15.f));
}

// scale factor that proj() applies to a vector with squared norm n2
__device__ __forceinline__ float proj_factor(float n2) {
    float n = fmaxf(sqrtf(n2), MIN_NORM);
    return (n > MAXNORM) ? (MAXNORM / n) : 1.f;
}

// hyp_bias = proj(expmap0(b, c), c) for both layers. 1 block x 64 threads.
__global__ void bias_kernel(const float* __restrict__ b1, const float* __restrict__ b2,
                            float* __restrict__ hb1, float* __restrict__ hb2) {
    int lane = threadIdx.x;
#pragma unroll
    for (int j = 0; j < 2; ++j) {
        const float* b = j ? b2 : b1;
        float* hb = j ? hb2 : hb1;
        float v0 = b[lane], v1 = b[lane + 64];
        float n2 = wave_sum(v0 * v0 + v1 * v1);
        float n = fmaxf(sqrtf(n2), MIN_NORM);
        float sc = tanh_c(n) / n;                 // expmap0
        sc *= proj_factor(sc * sc * n2);          // proj
        hb[lane] = v0 * sc;
        hb[lane + 64] = v1 * sc;
    }
}

// Fused: [optional encode proj(expmap0(x))] -> hyp_linear(W,b) -> logmap0
// One wave per row. W^T staged in LDS (pad stride 130 for float2 + banks).
template <bool PRELUDE>
__global__ __launch_bounds__(256)
void hyp_linear_tan(const float* __restrict__ xin, const float* __restrict__ W,
                    const float* __restrict__ hb, float* __restrict__ xtan, int n_rows) {
    __shared__ float sWT[128 * 130];
    __shared__ float sHB[128];
    __shared__ float sHB2;

    const int tid = threadIdx.x;
    for (int idx = tid; idx < 128 * 128; idx += 256) {
        int o = idx >> 7, i = idx & 127;
        sWT[i * 130 + o] = W[idx];                // transpose: sWT[in][out]
    }
    if (tid < 128) sHB[tid] = hb[tid];
    __syncthreads();
    if (tid < 64) {
        float v0 = sHB[tid], v1 = sHB[tid + 64];
        float s = wave_sum(v0 * v0 + v1 * v1);
        if (tid == 0) sHB2 = s;
    }
    __syncthreads();

    const int wid = tid >> 6;
    const int lane = tid & 63;
    const int l2 = lane << 1;
    const float y2 = sHB2;
    const float yb0 = sHB[l2], yb1 = sHB[l2 + 1];

    for (int row = blockIdx.x * 4 + wid; row < n_rows; row += gridDim.x * 4) {
        const float* xr = xin + (size_t)row * 128;
        float h0 = xr[lane], h1 = xr[lane + 64];

        if (PRELUDE) {  // encode: proj(expmap0(x))
            float n2 = wave_sum(h0 * h0 + h1 * h1);
            float n = fmaxf(sqrtf(n2), MIN_NORM);
            float sc = tanh_c(n) / n;
            sc *= proj_factor(sc * sc * n2);
            h0 *= sc; h1 *= sc;
        }

        // mobius_matvec
        float x2 = wave_sum(h0 * h0 + h1 * h1);
        float xn = fmaxf(sqrtf(x2), MIN_NORM);

        float acc0 = 0.f, acc1 = 0.f;
#pragma unroll 8
        for (int k = 0; k < 64; ++k) {
            float hk = __shfl(h0, k, 64);
            float2 w = *reinterpret_cast<const float2*>(&sWT[k * 130 + l2]);
            acc0 = fmaf(hk, w.x, acc0);
            acc1 = fmaf(hk, w.y, acc1);
        }
#pragma unroll 8
        for (int k = 0; k < 64; ++k) {
            float hk = __shfl(h1, k, 64);
            float2 w = *reinterpret_cast<const float2*>(&sWT[(k + 64) * 130 + l2]);
            acc0 = fmaf(hk, w.x, acc0);
            acc1 = fmaf(hk, w.y, acc1);
        }
        // lane holds mx columns (2*lane, 2*lane+1)
        float mxn2 = wave_sum(acc0 * acc0 + acc1 * acc1);
        float mxn = fmaxf(sqrtf(mxn2), MIN_NORM);
        float s = tanh_c(mxn / xn * artanh_c(xn));
        float scl = s / mxn;
        float m0 = acc0 * scl, m1 = acc1 * scl;
        float m2 = mxn2 * scl * scl;              // |res|^2 (exact algebra)
        float f = proj_factor(m2);                // proj
        m0 *= f; m1 *= f; m2 *= f * f;

        // mobius_add(m, hyp_bias)
        float xy = wave_sum(m0 * yb0 + m1 * yb1);
        float cx = 1.f + 2.f * xy + y2;
        float cy = 1.f - m2;
        float den = fmaxf(1.f + 2.f * xy + m2 * y2, MIN_NORM);
        float o0 = (cx * m0 + cy * yb0) / den;
        float o1 = (cx * m1 + cy * yb1) / den;

        // proj
        float on2 = wave_sum(o0 * o0 + o1 * o1);
        float f2 = proj_factor(on2);
        o0 *= f2; o1 *= f2; on2 *= f2 * f2;

        // logmap0 (start of hyp_agg)
        float onn = fmaxf(sqrtf(on2), MIN_NORM);
        float sl = artanh_c(onn) / onn;

        *reinterpret_cast<float2*>(&xtan[(size_t)row * 128 + l2]) =
            make_float2(o0 * sl, o1 * sl);
    }
}

// msg = ew * x_tan[src]; agg[dst] += msg  (atomic scatter, 32 threads/edge)
__global__ __launch_bounds__(256)
void agg_edges(const float* __restrict__ xtan, const int* __restrict__ src,
               const int* __restrict__ dst, const float* __restrict__ ew,
               float* __restrict__ agg, int n_edges) {
    int gt = blockIdx.x * blockDim.x + threadIdx.x;
    int e = gt >> 5;
    if (e >= n_edges) return;
    int c = (gt & 31) << 2;
    int sN = src[e], dN = dst[e];
    float w = ew[e];
    const float4 v = *reinterpret_cast<const float4*>(&xtan[(size_t)sN * 128 + c]);
    float* ap = &agg[(size_t)dN * 128 + c];
    atomicAdd(ap + 0, w * v.x);
    atomicAdd(ap + 1, w * v.y);
    atomicAdd(ap + 2, w * v.z);
    atomicAdd(ap + 3, w * v.w);
}

// Fused: h = proj(expmap0(agg)); xt = relu(logmap0(h)); out = proj(expmap0(xt))
__global__ __launch_bounds__(256)
void hyp_act_kernel(const float* __restrict__ in, float* __restrict__ out, int n_rows) {
    int row = blockIdx.x * 4 + (threadIdx.x >> 6);
    if (row >= n_rows) return;
    int lane = threadIdx.x & 63;
    int l2 = lane << 1;
    const float2 v = *reinterpret_cast<const float2*>(&in[(size_t)row * 128 + l2]);
    float a0 = v.x, a1 = v.y;

    // h = proj(expmap0(agg))
    float n2 = wave_sum(a0 * a0 + a1 * a1);
    float n = fmaxf(sqrtf(n2), MIN_NORM);
    float sc = tanh_c(n) / n;
    float hn2 = sc * sc * n2;
    float f = proj_factor(hn2);
    sc *= f; hn2 *= f * f;
    float h0 = a0 * sc, h1 = a1 * sc;

    // xt = relu(logmap0(h))
    float hn = fmaxf(sqrtf(hn2), MIN_NORM);
    float sl = artanh_c(hn) / hn;
    float x0 = fmaxf(h0 * sl, 0.f), x1 = fmaxf(h1 * sl, 0.f);

    // out = proj(expmap0(xt))
    float n2b = wave_sum(x0 * x0 + x1 * x1);
    float nb = fmaxf(sqrtf(n2b), MIN_NORM);
    float scb = tanh_c(nb) / nb;
    scb *= proj_factor(scb * scb * n2b);

    *reinterpret_cast<float2*>(&out[(size_t)row * 128 + l2]) =
        make_float2(x0 * scb, x1 * scb);
}

extern "C" void kernel_launch(void* const* d_in, const int* in_sizes, int n_in,
                              void* d_out, int out_size, void* d_ws, size_t ws_size,
                              hipStream_t stream) {
    const float* x   = (const float*)d_in[0];
    const int*   src = (const int*)d_in[1];
    const int*   dst = (const int*)d_in[2];
    const float* ew  = (const float*)d_in[3];
    const float* W1  = (const float*)d_in[4];
    const float* b1  = (const float*)d_in[5];
    const float* W2  = (const float*)d_in[6];
    const float* b2  = (const float*)d_in[7];

    const int N = in_sizes[0] / 128;
    const int E = in_sizes[1];

    float* ws   = (float*)d_ws;
    float* hb1  = ws;          // 128
    float* hb2  = ws + 128;    // 128
    float* nbuf = ws + 256;    // N*128 (agg1 / h3 / x_tan2)
    float* fout = (float*)d_out;

    const size_t node_bytes = (size_t)N * 128 * sizeof(float);
    const int agg_blocks = (E * 32 + 255) / 256;
    const int row_blocks = (N + 3) / 4;

    bias_kernel<<<1, 64, 0, stream>>>(b1, b2, hb1, hb2);

    // ---- layer 1 ----  (x_tan1 lives in d_out)
    hyp_linear_tan<true><<<512, 256, 0, stream>>>(x, W1, hb1, fout, N);
    hipMemsetAsync(nbuf, 0, node_bytes, stream);
    agg_edges<<<agg_blocks, 256, 0, stream>>>(fout, src, dst, ew, nbuf, E);
    hyp_act_kernel<<<row_blocks, 256, 0, stream>>>(nbuf, nbuf, N);

    // ---- layer 2 ----  (x_tan2 overwrites nbuf in place; agg2/final in d_out)
    hyp_linear_tan<false><<<512, 256, 0, stream>>>(nbuf, W2, hb2, nbuf, N);
    hipMemsetAsync(fout, 0, node_bytes, stream);
    agg_edges<<<agg_blocks, 256, 0, stream>>>(nbuf, src, dst, ew, fout, E);
    hyp_act_kernel<<<row_blocks, 256, 0, stream>>>(fout, fout, N);
}

// Round 2
// 385.786 us; speedup vs baseline: 5.4278x; 5.4278x over previous
//
#include <hip/hip_runtime.h>
#include <math.h>

#define MIN_NORM 1e-15f
#define MAXNORM  0.996f          /* (1 - 4e-3)/sqrt(c), c=1 */
#define ARTANH_CLIP 0.99999988f  /* float(1.0 - 1e-7) */

__device__ __forceinline__ float wave_sum(float v) {
#pragma unroll
    for (int off = 32; off > 0; off >>= 1) v += __shfl_xor(v, off, 64);
    return v;
}

__device__ __forceinline__ float artanh_c(float x) {
    x = fminf(fmaxf(x, -ARTANH_CLIP), ARTANH_CLIP);
    return 0.5f * (log1pf(x) - log1pf(-x));
}

__device__ __forceinline__ float tanh_c(float x) {
    return tanhf(fminf(fmaxf(x, -15.f), 15.f));
}

__device__ __forceinline__ float proj_factor(float n2) {
    float n = fmaxf(sqrtf(n2), MIN_NORM);
    return (n > MAXNORM) ? (MAXNORM / n) : 1.f;
}

// hyp_bias = proj(expmap0(b, c), c) for both layers. 1 block x 64 threads.
__global__ void bias_kernel(const float* __restrict__ b1, const float* __restrict__ b2,
                            float* __restrict__ hb1, float* __restrict__ hb2) {
    int lane = threadIdx.x;
#pragma unroll
    for (int j = 0; j < 2; ++j) {
        const float* b = j ? b2 : b1;
        float* hb = j ? hb2 : hb1;
        float v0 = b[lane], v1 = b[lane + 64];
        float n2 = wave_sum(v0 * v0 + v1 * v1);
        float n = fmaxf(sqrtf(n2), MIN_NORM);
        float sc = tanh_c(n) / n;
        sc *= proj_factor(sc * sc * n2);
        hb[lane] = v0 * sc;
        hb[lane + 64] = v1 * sc;
    }
}

// ---------------- CSR build ----------------

__global__ void hist_kernel(const int* __restrict__ dst, int* __restrict__ cnt, int E) {
    int e = blockIdx.x * blockDim.x + threadIdx.x;
    if (e < E) atomicAdd(&cnt[dst[e]], 1);
}

__global__ void scan1(const int* __restrict__ cnt, int* __restrict__ ptr,
                      int* __restrict__ bsum, int N) {
    __shared__ int s[256];
    const int t = threadIdx.x;
    const int i = blockIdx.x * 256 + t;
    int v = (i < N) ? cnt[i] : 0;
    s[t] = v;
    __syncthreads();
#pragma unroll
    for (int off = 1; off < 256; off <<= 1) {
        int add = (t >= off) ? s[t - off] : 0;
        __syncthreads();
        s[t] += add;
        __syncthreads();
    }
    if (i < N) ptr[i] = s[t] - v;          // exclusive within block
    if (t == 255) bsum[blockIdx.x] = s[255];
}

__global__ void scan2(const int* __restrict__ bsum, int* __restrict__ bscan, int nb) {
    __shared__ int s[256];
    const int t = threadIdx.x;
    int v = (t < nb) ? bsum[t] : 0;
    s[t] = v;
    __syncthreads();
#pragma unroll
    for (int off = 1; off < 256; off <<= 1) {
        int add = (t >= off) ? s[t - off] : 0;
        __syncthreads();
        s[t] += add;
        __syncthreads();
    }
    bscan[t] = s[t] - v;                   // exclusive block offsets
}

__global__ void scan3(const int* __restrict__ bscan, int* __restrict__ ptr,
                      int* __restrict__ cursor, int N, int E) {
    const int i = blockIdx.x * blockDim.x + threadIdx.x;
    if (i < N) {
        const int p = ptr[i] + bscan[i >> 8];
        ptr[i] = p;
        cursor[i] = p;
    }
    if (i == 0) ptr[N] = E;
}

__global__ void scatter_kernel(const int* __restrict__ src, const int* __restrict__ dst,
                               const float* __restrict__ ew, int* __restrict__ cursor,
                               uint2* __restrict__ epair, int E) {
    int e = blockIdx.x * blockDim.x + threadIdx.x;
    if (e >= E) return;
    int pos = atomicAdd(&cursor[dst[e]], 1);
    epair[pos] = make_uint2((unsigned)src[e], __float_as_uint(ew[e]));
}

// ---------------- fused linear (encode? -> mobius matvec -> +bias -> proj -> logmap0) ----------------
// 4 rows per wave, 16 rows per block iteration. x staged in LDS column-major
// (stride 18 floats: keeps 8B alignment for b64 reads, bounds write conflicts).
template <bool PRELUDE>
__global__ __launch_bounds__(256)
void hyp_linear_tan(const float* __restrict__ xin, const float* __restrict__ W,
                    const float* __restrict__ hb, float* __restrict__ xtan, int n_rows) {
    __shared__ float sWT[128 * 130];   // [k][o], pad 130
    __shared__ float sX[128 * 18];     // [k][row 0..15], stride 18
    __shared__ float sN2[16];
    __shared__ float sHB[128];
    __shared__ float sHB2;

    const int tid = threadIdx.x;
    for (int idx = tid; idx < 128 * 128; idx += 256) {
        int o = idx >> 7, k = idx & 127;
        sWT[k * 130 + o] = W[idx];     // transpose: [in][out]
    }
    if (tid < 128) sHB[tid] = hb[tid];
    __syncthreads();
    if (tid < 64) {
        float v0 = sHB[tid], v1 = sHB[tid + 64];
        float s = wave_sum(v0 * v0 + v1 * v1);
        if (tid == 0) sHB2 = s;
    }
    __syncthreads();

    const int wid = tid >> 6, lane = tid & 63, l2 = lane << 1;
    const float y2 = sHB2;
    const float yb0 = sHB[l2], yb1 = sHB[l2 + 1];
    const int srow = tid >> 4;         // 0..15: staging row
    const int schunk = tid & 15;       // 8-float chunk within row

    for (int base = blockIdx.x * 16; base < n_rows; base += gridDim.x * 16) {
        const int grow = base + srow;
        float4 a = make_float4(0.f, 0.f, 0.f, 0.f), b = a;
        if (grow < n_rows) {
            const float* xr = xin + (size_t)grow * 128 + schunk * 8;
            a = *reinterpret_cast<const float4*>(xr);
            b = *reinterpret_cast<const float4*>(xr + 4);
        }
        float ss = a.x * a.x + a.y * a.y + a.z * a.z + a.w * a.w
                 + b.x * b.x + b.y * b.y + b.z * b.z + b.w * b.w;
#pragma unroll
        for (int off = 1; off < 16; off <<= 1) ss += __shfl_xor(ss, off, 64);

        __syncthreads();               // previous iteration's sX reads done
        {
            const int kb = schunk * 8;
            sX[(kb + 0) * 18 + srow] = a.x;
            sX[(kb + 1) * 18 + srow] = a.y;
            sX[(kb + 2) * 18 + srow] = a.z;
            sX[(kb + 3) * 18 + srow] = a.w;
            sX[(kb + 4) * 18 + srow] = b.x;
            sX[(kb + 5) * 18 + srow] = b.y;
            sX[(kb + 6) * 18 + srow] = b.z;
            sX[(kb + 7) * 18 + srow] = b.w;
            if (schunk == 0) sN2[srow] = ss;
        }
        __syncthreads();

        float acc0[4] = {0.f, 0.f, 0.f, 0.f}, acc1[4] = {0.f, 0.f, 0.f, 0.f};
#pragma unroll 8
        for (int k = 0; k < 128; ++k) {
            const float2 xab = *reinterpret_cast<const float2*>(&sX[k * 18 + wid * 4]);
            const float2 xcd = *reinterpret_cast<const float2*>(&sX[k * 18 + wid * 4 + 2]);
            const float2 w   = *reinterpret_cast<const float2*>(&sWT[k * 130 + l2]);
            acc0[0] = fmaf(xab.x, w.x, acc0[0]); acc1[0] = fmaf(xab.x, w.y, acc1[0]);
            acc0[1] = fmaf(xab.y, w.x, acc0[1]); acc1[1] = fmaf(xab.y, w.y, acc1[1]);
            acc0[2] = fmaf(xcd.x, w.x, acc0[2]); acc1[2] = fmaf(xcd.x, w.y, acc1[2]);
            acc0[3] = fmaf(xcd.y, w.x, acc0[3]); acc1[3] = fmaf(xcd.y, w.y, acc1[3]);
        }

#pragma unroll
        for (int r = 0; r < 4; ++r) {
            const int row = base + wid * 4 + r;
            float m0 = acc0[r], m1 = acc1[r];        // raw = x @ W^T
            const float n2 = sN2[wid * 4 + r];
            const float n = fmaxf(sqrtf(n2), MIN_NORM);
            float sc = 1.f;
            if (PRELUDE) {                           // encode proj(expmap0(x)) as scalar
                sc = tanh_c(n) / n;
                sc *= proj_factor(sc * sc * n2);
            }
            const float xn = fmaxf(sc * n, MIN_NORM);
            const float rawn2 = wave_sum(m0 * m0 + m1 * m1);
            const float mxn = fmaxf(sc * sqrtf(rawn2), MIN_NORM);
            const float s = tanh_c(mxn / xn * artanh_c(xn));
            const float scl = (s * sc) / mxn;        // applies to raw
            m0 *= scl; m1 *= scl;
            float m2 = rawn2 * scl * scl;
            const float f = proj_factor(m2);
            m0 *= f; m1 *= f; m2 *= f * f;

            const float xy = wave_sum(m0 * yb0 + m1 * yb1);
            const float cx = 1.f + 2.f * xy + y2;
            const float cy = 1.f - m2;
            const float den = fmaxf(1.f + 2.f * xy + m2 * y2, MIN_NORM);
            float o0 = (cx * m0 + cy * yb0) / den;
            float o1 = (cx * m1 + cy * yb1) / den;

            float on2 = wave_sum(o0 * o0 + o1 * o1);
            const float f2 = proj_factor(on2);
            o0 *= f2; o1 *= f2; on2 *= f2 * f2;
            const float onn = fmaxf(sqrtf(on2), MIN_NORM);
            const float sl = artanh_c(onn) / onn;    // logmap0 (start of hyp_agg)
            if (row < n_rows)
                *reinterpret_cast<float2*>(&xtan[(size_t)row * 128 + l2]) =
                    make_float2(o0 * sl, o1 * sl);
        }
    }
}

// ---------------- gather aggregate + fused hyp_act ----------------
__global__ __launch_bounds__(256)
void gather_act(const float* __restrict__ xtan, const int* __restrict__ ptr,
                const uint2* __restrict__ epair, float* __restrict__ out, int n_rows) {
    const int v = blockIdx.x * 4 + (threadIdx.x >> 6);
    if (v >= n_rows) return;
    const int lane = threadIdx.x & 63, l2 = lane << 1;
    const int beg = ptr[v], end = ptr[v + 1];
    float a0 = 0.f, a1 = 0.f;
    int i = beg;
    for (; i + 1 < end; i += 2) {
        const uint2 p0 = epair[i], p1 = epair[i + 1];
        const float2 x0 = *reinterpret_cast<const float2*>(&xtan[(size_t)p0.x * 128 + l2]);
        const float2 x1 = *reinterpret_cast<const float2*>(&xtan[(size_t)p1.x * 128 + l2]);
        const float w0 = __uint_as_float(p0.y), w1 = __uint_as_float(p1.y);
        a0 = fmaf(w0, x0.x, a0); a1 = fmaf(w0, x0.y, a1);
        a0 = fmaf(w1, x1.x, a0); a1 = fmaf(w1, x1.y, a1);
    }
    if (i < end) {
        const uint2 p = epair[i];
        const float2 xv = *reinterpret_cast<const float2*>(&xtan[(size_t)p.x * 128 + l2]);
        const float w = __uint_as_float(p.y);
        a0 = fmaf(w, xv.x, a0); a1 = fmaf(w, xv.y, a1);
    }

    // h = proj(expmap0(agg)); xt = relu(logmap0(h)); out = proj(expmap0(xt))
    float n2 = wave_sum(a0 * a0 + a1 * a1);
    float n = fmaxf(sqrtf(n2), MIN_NORM);
    float sc = tanh_c(n) / n;
    float hn2 = sc * sc * n2;
    float f = proj_factor(hn2);
    sc *= f; hn2 *= f * f;
    float h0 = a0 * sc, h1 = a1 * sc;
    float hn = fmaxf(sqrtf(hn2), MIN_NORM);
    float sl = artanh_c(hn) / hn;
    float x0 = fmaxf(h0 * sl, 0.f), x1 = fmaxf(h1 * sl, 0.f);
    float n2b = wave_sum(x0 * x0 + x1 * x1);
    float nb = fmaxf(sqrtf(n2b), MIN_NORM);
    float scb = tanh_c(nb) / nb;
    scb *= proj_factor(scb * scb * n2b);
    *reinterpret_cast<float2*>(&out[(size_t)v * 128 + l2]) =
        make_float2(x0 * scb, x1 * scb);
}

// ---------------- fallback (R1 atomic path) ----------------
__global__ __launch_bounds__(256)
void agg_edges(const float* __restrict__ xtan, const int* __restrict__ src,
               const int* __restrict__ dst, const float* __restrict__ ew,
               float* __restrict__ agg, int n_edges) {
    int gt = blockIdx.x * blockDim.x + threadIdx.x;
    int e = gt >> 5;
    if (e >= n_edges) return;
    int c = (gt & 31) << 2;
    int sN = src[e], dN = dst[e];
    float w = ew[e];
    const float4 v = *reinterpret_cast<const float4*>(&xtan[(size_t)sN * 128 + c]);
    float* ap = &agg[(size_t)dN * 128 + c];
    atomicAdd(ap + 0, w * v.x);
    atomicAdd(ap + 1, w * v.y);
    atomicAdd(ap + 2, w * v.z);
    atomicAdd(ap + 3, w * v.w);
}

__global__ __launch_bounds__(256)
void hyp_act_kernel(const float* __restrict__ in, float* __restrict__ out, int n_rows) {
    int row = blockIdx.x * 4 + (threadIdx.x >> 6);
    if (row >= n_rows) return;
    int lane = threadIdx.x & 63;
    int l2 = lane << 1;
    const float2 v = *reinterpret_cast<const float2*>(&in[(size_t)row * 128 + l2]);
    float a0 = v.x, a1 = v.y;
    float n2 = wave_sum(a0 * a0 + a1 * a1);
    float n = fmaxf(sqrtf(n2), MIN_NORM);
    float sc = tanh_c(n) / n;
    float hn2 = sc * sc * n2;
    float f = proj_factor(hn2);
    sc *= f; hn2 *= f * f;
    float h0 = a0 * sc, h1 = a1 * sc;
    float hn = fmaxf(sqrtf(hn2), MIN_NORM);
    float sl = artanh_c(hn) / hn;
    float x0 = fmaxf(h0 * sl, 0.f), x1 = fmaxf(h1 * sl, 0.f);
    float n2b = wave_sum(x0 * x0 + x1 * x1);
    float nb = fmaxf(sqrtf(n2b), MIN_NORM);
    float scb = tanh_c(nb) / nb;
    scb *= proj_factor(scb * scb * n2b);
    *reinterpret_cast<float2*>(&out[(size_t)row * 128 + l2]) =
        make_float2(x0 * scb, x1 * scb);
}

extern "C" void kernel_launch(void* const* d_in, const int* in_sizes, int n_in,
                              void* d_out, int out_size, void* d_ws, size_t ws_size,
                              hipStream_t stream) {
    const float* x   = (const float*)d_in[0];
    const int*   src = (const int*)d_in[1];
    const int*   dst = (const int*)d_in[2];
    const float* ew  = (const float*)d_in[3];
    const float* W1  = (const float*)d_in[4];
    const float* b1  = (const float*)d_in[5];
    const float* W2  = (const float*)d_in[6];
    const float* b2  = (const float*)d_in[7];

    const int N = in_sizes[0] / 128;
    const int E = in_sizes[1];
    float* fout = (float*)d_out;

    const size_t need = (size_t)N * 128 * 4        // nbuf (16B-aligned at base)
                      + (size_t)E * 8              // epair
                      + ((size_t)(N + 1) + N + N + 512) * 4
                      + 256 * 4;                   // hb1/hb2

    if (ws_size >= need) {
        float* nbuf  = (float*)d_ws;
        uint2* epair = (uint2*)(nbuf + (size_t)N * 128);
        int* ptr     = (int*)(epair + E);
        int* cnt     = ptr + (N + 1);
        int* cursor  = cnt + N;
        int* bsum    = cursor + N;
        int* bscan   = bsum + 256;
        float* hb1   = (float*)(bscan + 256);
        float* hb2   = hb1 + 128;

        const int nbE = (E + 255) / 256;
        const int nbN = (N + 255) / 256;

        bias_kernel<<<1, 64, 0, stream>>>(b1, b2, hb1, hb2);

        // build CSR by dst (graph reused by both layers)
        hipMemsetAsync(cnt, 0, (size_t)N * 4, stream);
        hist_kernel<<<nbE, 256, 0, stream>>>(dst, cnt, E);
        scan1<<<nbN, 256, 0, stream>>>(cnt, ptr, bsum, N);
        scan2<<<1, 256, 0, stream>>>(bsum, bscan, nbN);
        scan3<<<nbN, 256, 0, stream>>>(bscan, ptr, cursor, N, E);
        scatter_kernel<<<nbE, 256, 0, stream>>>(src, dst, ew, cursor, epair, E);

        // layer 1 (x_tan1 in d_out)
        hyp_linear_tan<true><<<512, 256, 0, stream>>>(x, W1, hb1, fout, N);
        gather_act<<<(N + 3) / 4, 256, 0, stream>>>(fout, ptr, epair, nbuf, N);
        // layer 2 (x_tan2 in-place in nbuf; final in d_out)
        hyp_linear_tan<false><<<512, 256, 0, stream>>>(nbuf, W2, hb2, nbuf, N);
        gather_act<<<(N + 3) / 4, 256, 0, stream>>>(nbuf, ptr, epair, fout, N);
    } else {
        // fallback: R1 atomic-scatter path
        float* nbuf = (float*)d_ws;
        float* hb1  = nbuf + (size_t)N * 128;
        float* hb2  = hb1 + 128;
        const size_t node_bytes = (size_t)N * 128 * sizeof(float);
        const int agg_blocks = (int)(((size_t)E * 32 + 255) / 256);
        const int row_blocks = (N + 3) / 4;

        bias_kernel<<<1, 64, 0, stream>>>(b1, b2, hb1, hb2);
        hyp_linear_tan<true><<<512, 256, 0, stream>>>(x, W1, hb1, fout, N);
        hipMemsetAsync(nbuf, 0, node_bytes, stream);
        agg_edges<<<agg_blocks, 256, 0, stream>>>(fout, src, dst, ew, nbuf, E);
        hyp_act_kernel<<<row_blocks, 256, 0, stream>>>(nbuf, nbuf, N);
        hyp_linear_tan<false><<<512, 256, 0, stream>>>(nbuf, W2, hb2, nbuf, N);
        hipMemsetAsync(fout, 0, node_bytes, stream);
        agg_edges<<<agg_blocks, 256, 0, stream>>>(nbuf, src, dst, ew, fout, E);
        hyp_act_kernel<<<row_blocks, 256, 0, stream>>>(fout, fout, N);
    }
}

// Round 3
// 384.577 us; speedup vs baseline: 5.4449x; 1.0031x over previous
//
#include <hip/hip_runtime.h>
#include <math.h>

#define MIN_NORM 1e-15f
#define MAXNORM  0.996f          /* (1 - 4e-3)/sqrt(c), c=1 */
#define ARTANH_CLIP 0.99999988f  /* float(1.0 - 1e-7) */

__device__ __forceinline__ float wave_sum(float v) {
#pragma unroll
    for (int off = 32; off > 0; off >>= 1) v += __shfl_xor(v, off, 64);
    return v;
}

__device__ __forceinline__ float artanh_c(float x) {
    x = fminf(fmaxf(x, -ARTANH_CLIP), ARTANH_CLIP);
    return 0.5f * (log1pf(x) - log1pf(-x));
}

__device__ __forceinline__ float tanh_c(float x) {
    return tanhf(fminf(fmaxf(x, -15.f), 15.f));
}

__device__ __forceinline__ float proj_factor(float n2) {
    float n = fmaxf(sqrtf(n2), MIN_NORM);
    return (n > MAXNORM) ? (MAXNORM / n) : 1.f;
}

// hyp_bias = proj(expmap0(b, c), c) for both layers. 1 block x 64 threads.
__global__ void bias_kernel(const float* __restrict__ b1, const float* __restrict__ b2,
                            float* __restrict__ hb1, float* __restrict__ hb2) {
    int lane = threadIdx.x;
#pragma unroll
    for (int j = 0; j < 2; ++j) {
        const float* b = j ? b2 : b1;
        float* hb = j ? hb2 : hb1;
        float v0 = b[lane], v1 = b[lane + 64];
        float n2 = wave_sum(v0 * v0 + v1 * v1);
        float n = fmaxf(sqrtf(n2), MIN_NORM);
        float sc = tanh_c(n) / n;
        sc *= proj_factor(sc * sc * n2);
        hb[lane] = v0 * sc;
        hb[lane + 64] = v1 * sc;
    }
}

// ---------------- CSR build ----------------

__global__ void hist_kernel(const int* __restrict__ dst, int* __restrict__ cnt, int E) {
    int e = blockIdx.x * blockDim.x + threadIdx.x;
    if (e < E) atomicAdd(&cnt[dst[e]], 1);
}

__global__ void scan1(const int* __restrict__ cnt, int* __restrict__ ptr,
                      int* __restrict__ bsum, int N) {
    __shared__ int s[256];
    const int t = threadIdx.x;
    const int i = blockIdx.x * 256 + t;
    int v = (i < N) ? cnt[i] : 0;
    s[t] = v;
    __syncthreads();
#pragma unroll
    for (int off = 1; off < 256; off <<= 1) {
        int add = (t >= off) ? s[t - off] : 0;
        __syncthreads();
        s[t] += add;
        __syncthreads();
    }
    if (i < N) ptr[i] = s[t] - v;          // exclusive within block
    if (t == 255) bsum[blockIdx.x] = s[255];
}

__global__ void scan2(const int* __restrict__ bsum, int* __restrict__ bscan, int nb) {
    __shared__ int s[256];
    const int t = threadIdx.x;
    int v = (t < nb) ? bsum[t] : 0;
    s[t] = v;
    __syncthreads();
#pragma unroll
    for (int off = 1; off < 256; off <<= 1) {
        int add = (t >= off) ? s[t - off] : 0;
        __syncthreads();
        s[t] += add;
        __syncthreads();
    }
    bscan[t] = s[t] - v;                   // exclusive block offsets
}

__global__ void scan3(const int* __restrict__ bscan, int* __restrict__ ptr,
                      int* __restrict__ cursor, int N, int E) {
    const int i = blockIdx.x * blockDim.x + threadIdx.x;
    if (i < N) {
        const int p = ptr[i] + bscan[i >> 8];
        ptr[i] = p;
        cursor[i] = p;
    }
    if (i == 0) ptr[N] = E;
}

__global__ void scatter_kernel(const int* __restrict__ src, const int* __restrict__ dst,
                               const float* __restrict__ ew, int* __restrict__ cursor,
                               uint2* __restrict__ epair, int E) {
    int e = blockIdx.x * blockDim.x + threadIdx.x;
    if (e >= E) return;
    int pos = atomicAdd(&cursor[dst[e]], 1);
    epair[pos] = make_uint2((unsigned)src[e], __float_as_uint(ew[e]));
}

// ---------------- fused linear (encode? -> mobius matvec -> +bias -> proj -> logmap0) ----------------
// 4 rows per wave, 16 rows per block iteration. x staged in LDS column-major
// (stride 18 floats: keeps 8B alignment for b64 reads, bounds write conflicts).
template <bool PRELUDE>
__global__ __launch_bounds__(256)
void hyp_linear_tan(const float* __restrict__ xin, const float* __restrict__ W,
                    const float* __restrict__ hb, float* __restrict__ xtan, int n_rows) {
    __shared__ float sWT[128 * 130];   // [k][o], pad 130
    __shared__ float sX[128 * 18];     // [k][row 0..15], stride 18
    __shared__ float sN2[16];
    __shared__ float sHB[128];
    __shared__ float sHB2;

    const int tid = threadIdx.x;
    for (int idx = tid; idx < 128 * 128; idx += 256) {
        int o = idx >> 7, k = idx & 127;
        sWT[k * 130 + o] = W[idx];     // transpose: [in][out]
    }
    if (tid < 128) sHB[tid] = hb[tid];
    __syncthreads();
    if (tid < 64) {
        float v0 = sHB[tid], v1 = sHB[tid + 64];
        float s = wave_sum(v0 * v0 + v1 * v1);
        if (tid == 0) sHB2 = s;
    }
    __syncthreads();

    const int wid = tid >> 6, lane = tid & 63, l2 = lane << 1;
    const float y2 = sHB2;
    const float yb0 = sHB[l2], yb1 = sHB[l2 + 1];
    const int srow = tid >> 4;         // 0..15: staging row
    const int schunk = tid & 15;       // 8-float chunk within row

    for (int base = blockIdx.x * 16; base < n_rows; base += gridDim.x * 16) {
        const int grow = base + srow;
        float4 a = make_float4(0.f, 0.f, 0.f, 0.f), b = a;
        if (grow < n_rows) {
            const float* xr = xin + (size_t)grow * 128 + schunk * 8;
            a = *reinterpret_cast<const float4*>(xr);
            b = *reinterpret_cast<const float4*>(xr + 4);
        }
        float ss = a.x * a.x + a.y * a.y + a.z * a.z + a.w * a.w
                 + b.x * b.x + b.y * b.y + b.z * b.z + b.w * b.w;
#pragma unroll
        for (int off = 1; off < 16; off <<= 1) ss += __shfl_xor(ss, off, 64);

        __syncthreads();               // previous iteration's sX reads done
        {
            const int kb = schunk * 8;
            sX[(kb + 0) * 18 + srow] = a.x;
            sX[(kb + 1) * 18 + srow] = a.y;
            sX[(kb + 2) * 18 + srow] = a.z;
            sX[(kb + 3) * 18 + srow] = a.w;
            sX[(kb + 4) * 18 + srow] = b.x;
            sX[(kb + 5) * 18 + srow] = b.y;
            sX[(kb + 6) * 18 + srow] = b.z;
            sX[(kb + 7) * 18 + srow] = b.w;
            if (schunk == 0) sN2[srow] = ss;
        }
        __syncthreads();

        float acc0[4] = {0.f, 0.f, 0.f, 0.f}, acc1[4] = {0.f, 0.f, 0.f, 0.f};
#pragma unroll 8
        for (int k = 0; k < 128; ++k) {
            const float2 xab = *reinterpret_cast<const float2*>(&sX[k * 18 + wid * 4]);
            const float2 xcd = *reinterpret_cast<const float2*>(&sX[k * 18 + wid * 4 + 2]);
            const float2 w   = *reinterpret_cast<const float2*>(&sWT[k * 130 + l2]);
            acc0[0] = fmaf(xab.x, w.x, acc0[0]); acc1[0] = fmaf(xab.x, w.y, acc1[0]);
            acc0[1] = fmaf(xab.y, w.x, acc0[1]); acc1[1] = fmaf(xab.y, w.y, acc1[1]);
            acc0[2] = fmaf(xcd.x, w.x, acc0[2]); acc1[2] = fmaf(xcd.x, w.y, acc1[2]);
            acc0[3] = fmaf(xcd.y, w.x, acc0[3]); acc1[3] = fmaf(xcd.y, w.y, acc1[3]);
        }

#pragma unroll
        for (int r = 0; r < 4; ++r) {
            const int row = base + wid * 4 + r;
            float m0 = acc0[r], m1 = acc1[r];        // raw = x @ W^T
            const float n2 = sN2[wid * 4 + r];
            const float n = fmaxf(sqrtf(n2), MIN_NORM);
            float sc = 1.f;
            if (PRELUDE) {                           // encode proj(expmap0(x)) as scalar
                sc = tanh_c(n) / n;
                sc *= proj_factor(sc * sc * n2);
            }
            const float xn = fmaxf(sc * n, MIN_NORM);
            const float rawn2 = wave_sum(m0 * m0 + m1 * m1);
            const float mxn = fmaxf(sc * sqrtf(rawn2), MIN_NORM);
            const float s = tanh_c(mxn / xn * artanh_c(xn));
            const float scl = (s * sc) / mxn;        // applies to raw
            m0 *= scl; m1 *= scl;
            float m2 = rawn2 * scl * scl;
            const float f = proj_factor(m2);
            m0 *= f; m1 *= f; m2 *= f * f;

            const float xy = wave_sum(m0 * yb0 + m1 * yb1);
            const float cx = 1.f + 2.f * xy + y2;
            const float cy = 1.f - m2;
            const float den = fmaxf(1.f + 2.f * xy + m2 * y2, MIN_NORM);
            float o0 = (cx * m0 + cy * yb0) / den;
            float o1 = (cx * m1 + cy * yb1) / den;

            float on2 = wave_sum(o0 * o0 + o1 * o1);
            const float f2 = proj_factor(on2);
            o0 *= f2; o1 *= f2; on2 *= f2 * f2;
            const float onn = fmaxf(sqrtf(on2), MIN_NORM);
            const float sl = artanh_c(onn) / onn;    // logmap0 (start of hyp_agg)
            if (row < n_rows)
                *reinterpret_cast<float2*>(&xtan[(size_t)row * 128 + l2]) =
                    make_float2(o0 * sl, o1 * sl);
        }
    }
}

// ---------------- gather aggregate + fused hyp_act ----------------
__global__ __launch_bounds__(256)
void gather_act(const float* __restrict__ xtan, const int* __restrict__ ptr,
                const uint2* __restrict__ epair, float* __restrict__ out, int n_rows) {
    const int v = blockIdx.x * 4 + (threadIdx.x >> 6);
    if (v >= n_rows) return;
    const int lane = threadIdx.x & 63, l2 = lane << 1;
    const int beg = ptr[v], end = ptr[v + 1];
    float a0 = 0.f, a1 = 0.f;
    int i = beg;
    for (; i + 1 < end; i += 2) {
        const uint2 p0 = epair[i], p1 = epair[i + 1];
        const float2 x0 = *reinterpret_cast<const float2*>(&xtan[(size_t)p0.x * 128 + l2]);
        const float2 x1 = *reinterpret_cast<const float2*>(&xtan[(size_t)p1.x * 128 + l2]);
        const float w0 = __uint_as_float(p0.y), w1 = __uint_as_float(p1.y);
        a0 = fmaf(w0, x0.x, a0); a1 = fmaf(w0, x0.y, a1);
        a0 = fmaf(w1, x1.x, a0); a1 = fmaf(w1, x1.y, a1);
    }
    if (i < end) {
        const uint2 p = epair[i];
        const float2 xv = *reinterpret_cast<const float2*>(&xtan[(size_t)p.x * 128 + l2]);
        const float w = __uint_as_float(p.y);
        a0 = fmaf(w, xv.x, a0); a1 = fmaf(w, xv.y, a1);
    }

    // h = proj(expmap0(agg)); xt = relu(logmap0(h)); out = proj(expmap0(xt))
    float n2 = wave_sum(a0 * a0 + a1 * a1);
    float n = fmaxf(sqrtf(n2), MIN_NORM);
    float sc = tanh_c(n) / n;
    float hn2 = sc * sc * n2;
    float f = proj_factor(hn2);
    sc *= f; hn2 *= f * f;
    float h0 = a0 * sc, h1 = a1 * sc;
    float hn = fmaxf(sqrtf(hn2), MIN_NORM);
    float sl = artanh_c(hn) / hn;
    float x0 = fmaxf(h0 * sl, 0.f), x1 = fmaxf(h1 * sl, 0.f);
    float n2b = wave_sum(x0 * x0 + x1 * x1);
    float nb = fmaxf(sqrtf(n2b), MIN_NORM);
    float scb = tanh_c(nb) / nb;
    scb *= proj_factor(scb * scb * n2b);
    *reinterpret_cast<float2*>(&out[(size_t)v * 128 + l2]) =
        make_float2(x0 * scb, x1 * scb);
}

// ---------------- fallback (R1 atomic path) ----------------
__global__ __launch_bounds__(256)
void agg_edges(const float* __restrict__ xtan, const int* __restrict__ src,
               const int* __restrict__ dst, const float* __restrict__ ew,
               float* __restrict__ agg, int n_edges) {
    int gt = blockIdx.x * blockDim.x + threadIdx.x;
    int e = gt >> 5;
    if (e >= n_edges) return;
    int c = (gt & 31) << 2;
    int sN = src[e], dN = dst[e];
    float w = ew[e];
    const float4 v = *reinterpret_cast<const float4*>(&xtan[(size_t)sN * 128 + c]);
    float* ap = &agg[(size_t)dN * 128 + c];
    atomicAdd(ap + 0, w * v.x);
    atomicAdd(ap + 1, w * v.y);
    atomicAdd(ap + 2, w * v.z);
    atomicAdd(ap + 3, w * v.w);
}

__global__ __launch_bounds__(256)
void hyp_act_kernel(const float* __restrict__ in, float* __restrict__ out, int n_rows) {
    int row = blockIdx.x * 4 + (threadIdx.x >> 6);
    if (row >= n_rows) return;
    int lane = threadIdx.x & 63;
    int l2 = lane << 1;
    const float2 v = *reinterpret_cast<const float2*>(&in[(size_t)row * 128 + l2]);
    float a0 = v.x, a1 = v.y;
    float n2 = wave_sum(a0 * a0 + a1 * a1);
    float n = fmaxf(sqrtf(n2), MIN_NORM);
    float sc = tanh_c(n) / n;
    float hn2 = sc * sc * n2;
    float f = proj_factor(hn2);
    sc *= f; hn2 *= f * f;
    float h0 = a0 * sc, h1 = a1 * sc;
    float hn = fmaxf(sqrtf(hn2), MIN_NORM);
    float sl = artanh_c(hn) / hn;
    float x0 = fmaxf(h0 * sl, 0.f), x1 = fmaxf(h1 * sl, 0.f);
    float n2b = wave_sum(x0 * x0 + x1 * x1);
    float nb = fmaxf(sqrtf(n2b), MIN_NORM);
    float scb = tanh_c(nb) / nb;
    scb *= proj_factor(scb * scb * n2b);
    *reinterpret_cast<float2*>(&out[(size_t)row * 128 + l2]) =
        make_float2(x0 * scb, x1 * scb);
}

extern "C" void kernel_launch(void* const* d_in, const int* in_sizes, int n_in,
                              void* d_out, int out_size, void* d_ws, size_t ws_size,
                              hipStream_t stream) {
    const float* x   = (const float*)d_in[0];
    const int*   src = (const int*)d_in[1];
    const int*   dst = (const int*)d_in[2];
    const float* ew  = (const float*)d_in[3];
    const float* W1  = (const float*)d_in[4];
    const float* b1  = (const float*)d_in[5];
    const float* W2  = (const float*)d_in[6];
    const float* b2  = (const float*)d_in[7];

    const int N = in_sizes[0] / 128;
    const int E = in_sizes[1];
    float* fout = (float*)d_out;

    const size_t need = (size_t)N * 128 * 4        // nbuf (16B-aligned at base)
                      + (size_t)E * 8              // epair
                      + ((size_t)(N + 1) + N + N + 512) * 4
                      + 256 * 4;                   // hb1/hb2

    if (ws_size >= need) {
        float* nbuf  = (float*)d_ws;
        uint2* epair = (uint2*)(nbuf + (size_t)N * 128);
        int* ptr     = (int*)(epair + E);
        int* cnt     = ptr + (N + 1);
        int* cursor  = cnt + N;
        int* bsum    = cursor + N;
        int* bscan   = bsum + 256;
        float* hb1   = (float*)(bscan + 256);
        float* hb2   = hb1 + 128;

        const int nbE = (E + 255) / 256;
        const int nbN = (N + 255) / 256;

        bias_kernel<<<1, 64, 0, stream>>>(b1, b2, hb1, hb2);

        // build CSR by dst (graph reused by both layers)
        hipMemsetAsync(cnt, 0, (size_t)N * 4, stream);
        hist_kernel<<<nbE, 256, 0, stream>>>(dst, cnt, E);
        scan1<<<nbN, 256, 0, stream>>>(cnt, ptr, bsum, N);
        scan2<<<1, 256, 0, stream>>>(bsum, bscan, nbN);
        scan3<<<nbN, 256, 0, stream>>>(bscan, ptr, cursor, N, E);
        scatter_kernel<<<nbE, 256, 0, stream>>>(src, dst, ew, cursor, epair, E);

        // layer 1 (x_tan1 in d_out)
        hyp_linear_tan<true><<<512, 256, 0, stream>>>(x, W1, hb1, fout, N);
        gather_act<<<(N + 3) / 4, 256, 0, stream>>>(fout, ptr, epair, nbuf, N);
        // layer 2 (x_tan2 in-place in nbuf; final in d_out)
        hyp_linear_tan<false><<<512, 256, 0, stream>>>(nbuf, W2, hb2, nbuf, N);
        gather_act<<<(N + 3) / 4, 256, 0, stream>>>(nbuf, ptr, epair, fout, N);
    } else {
        // fallback: R1 atomic-scatter path
        float* nbuf = (float*)d_ws;
        float* hb1  = nbuf + (size_t)N * 128;
        float* hb2  = hb1 + 128;
        const size_t node_bytes = (size_t)N * 128 * sizeof(float);
        const int agg_blocks = (int)(((size_t)E * 32 + 255) / 256);
        const int row_blocks = (N + 3) / 4;

        bias_kernel<<<1, 64, 0, stream>>>(b1, b2, hb1, hb2);
        hyp_linear_tan<true><<<512, 256, 0, stream>>>(x, W1, hb1, fout, N);
        hipMemsetAsync(nbuf, 0, node_bytes, stream);
        agg_edges<<<agg_blocks, 256, 0, stream>>>(fout, src, dst, ew, nbuf, E);
        hyp_act_kernel<<<row_blocks, 256, 0, stream>>>(nbuf, nbuf, N);
        hyp_linear_tan<false><<<512, 256, 0, stream>>>(nbuf, W2, hb2, nbuf, N);
        hipMemsetAsync(fout, 0, node_bytes, stream);
        agg_edges<<<agg_blocks, 256, 0, stream>>>(nbuf, src, dst, ew, fout, E);
        hyp_act_kernel<<<row_blocks, 256, 0, stream>>>(fout, fout, N);
    }
}

// Round 4
// 384.261 us; speedup vs baseline: 5.4493x; 1.0008x over previous
//
#include <hip/hip_runtime.h>
#include <math.h>

#define MIN_NORM 1e-15f
#define MAXNORM  0.996f          /* (1 - 4e-3)/sqrt(c), c=1 */
#define ARTANH_CLIP 0.99999988f  /* float(1.0 - 1e-7) */

__device__ __forceinline__ float wave_sum(float v) {
#pragma unroll
    for (int off = 32; off > 0; off >>= 1) v += __shfl_xor(v, off, 64);
    return v;
}

__device__ __forceinline__ float artanh_c(float x) {
    x = fminf(fmaxf(x, -ARTANH_CLIP), ARTANH_CLIP);
    return 0.5f * (log1pf(x) - log1pf(-x));
}

__device__ __forceinline__ float tanh_c(float x) {
    return tanhf(fminf(fmaxf(x, -15.f), 15.f));
}

__device__ __forceinline__ float proj_factor(float n2) {
    float n = fmaxf(sqrtf(n2), MIN_NORM);
    return (n > MAXNORM) ? (MAXNORM / n) : 1.f;
}

// hyp_bias = proj(expmap0(b, c), c) for both layers. 1 block x 64 threads.
__global__ void bias_kernel(const float* __restrict__ b1, const float* __restrict__ b2,
                            float* __restrict__ hb1, float* __restrict__ hb2) {
    int lane = threadIdx.x;
#pragma unroll
    for (int j = 0; j < 2; ++j) {
        const float* b = j ? b2 : b1;
        float* hb = j ? hb2 : hb1;
        float v0 = b[lane], v1 = b[lane + 64];
        float n2 = wave_sum(v0 * v0 + v1 * v1);
        float n = fmaxf(sqrtf(n2), MIN_NORM);
        float sc = tanh_c(n) / n;
        sc *= proj_factor(sc * sc * n2);
        hb[lane] = v0 * sc;
        hb[lane + 64] = v1 * sc;
    }
}

// ---------------- CSR build ----------------

__global__ void hist_kernel(const int* __restrict__ dst, int* __restrict__ cnt, int E) {
    int e = blockIdx.x * blockDim.x + threadIdx.x;
    if (e < E) atomicAdd(&cnt[dst[e]], 1);
}

__global__ void scan1(const int* __restrict__ cnt, int* __restrict__ ptr,
                      int* __restrict__ bsum, int N) {
    __shared__ int s[256];
    const int t = threadIdx.x;
    const int i = blockIdx.x * 256 + t;
    int v = (i < N) ? cnt[i] : 0;
    s[t] = v;
    __syncthreads();
#pragma unroll
    for (int off = 1; off < 256; off <<= 1) {
        int add = (t >= off) ? s[t - off] : 0;
        __syncthreads();
        s[t] += add;
        __syncthreads();
    }
    if (i < N) ptr[i] = s[t] - v;          // exclusive within block
    if (t == 255) bsum[blockIdx.x] = s[255];
}

__global__ void scan2(const int* __restrict__ bsum, int* __restrict__ bscan, int nb) {
    __shared__ int s[256];
    const int t = threadIdx.x;
    int v = (t < nb) ? bsum[t] : 0;
    s[t] = v;
    __syncthreads();
#pragma unroll
    for (int off = 1; off < 256; off <<= 1) {
        int add = (t >= off) ? s[t - off] : 0;
        __syncthreads();
        s[t] += add;
        __syncthreads();
    }
    bscan[t] = s[t] - v;                   // exclusive block offsets
}

__global__ void scan3(const int* __restrict__ bscan, int* __restrict__ ptr,
                      int* __restrict__ cursor, int N, int E) {
    const int i = blockIdx.x * blockDim.x + threadIdx.x;
    if (i < N) {
        const int p = ptr[i] + bscan[i >> 8];
        ptr[i] = p;
        cursor[i] = p;
    }
    if (i == 0) ptr[N] = E;
}

__global__ void scatter_kernel(const int* __restrict__ src, const int* __restrict__ dst,
                               const float* __restrict__ ew, int* __restrict__ cursor,
                               uint2* __restrict__ epair, int E) {
    int e = blockIdx.x * blockDim.x + threadIdx.x;
    if (e >= E) return;
    int pos = atomicAdd(&cursor[dst[e]], 1);
    epair[pos] = make_uint2((unsigned)src[e], __float_as_uint(ew[e]));
}

// ---------------- fused linear (encode? -> mobius matvec -> +bias -> proj -> logmap0) ----------------
// 4 rows per wave, 16 rows per block iteration. x staged in LDS column-major
// (stride 18 floats: keeps 8B alignment for b64 reads, bounds write conflicts).
template <bool PRELUDE>
__global__ __launch_bounds__(256)
void hyp_linear_tan(const float* __restrict__ xin, const float* __restrict__ W,
                    const float* __restrict__ hb, float* __restrict__ xtan, int n_rows) {
    __shared__ float sWT[128 * 130];   // [k][o], pad 130
    __shared__ float sX[128 * 18];     // [k][row 0..15], stride 18
    __shared__ float sN2[16];
    __shared__ float sHB[128];
    __shared__ float sHB2;

    const int tid = threadIdx.x;
    for (int idx = tid; idx < 128 * 128; idx += 256) {
        int o = idx >> 7, k = idx & 127;
        sWT[k * 130 + o] = W[idx];     // transpose: [in][out]
    }
    if (tid < 128) sHB[tid] = hb[tid];
    __syncthreads();
    if (tid < 64) {
        float v0 = sHB[tid], v1 = sHB[tid + 64];
        float s = wave_sum(v0 * v0 + v1 * v1);
        if (tid == 0) sHB2 = s;
    }
    __syncthreads();

    const int wid = tid >> 6, lane = tid & 63, l2 = lane << 1;
    const float y2 = sHB2;
    const float yb0 = sHB[l2], yb1 = sHB[l2 + 1];
    const int srow = tid >> 4;         // 0..15: staging row
    const int schunk = tid & 15;       // 8-float chunk within row

    for (int base = blockIdx.x * 16; base < n_rows; base += gridDim.x * 16) {
        const int grow = base + srow;
        float4 a = make_float4(0.f, 0.f, 0.f, 0.f), b = a;
        if (grow < n_rows) {
            const float* xr = xin + (size_t)grow * 128 + schunk * 8;
            a = *reinterpret_cast<const float4*>(xr);
            b = *reinterpret_cast<const float4*>(xr + 4);
        }
        float ss = a.x * a.x + a.y * a.y + a.z * a.z + a.w * a.w
                 + b.x * b.x + b.y * b.y + b.z * b.z + b.w * b.w;
#pragma unroll
        for (int off = 1; off < 16; off <<= 1) ss += __shfl_xor(ss, off, 64);

        __syncthreads();               // previous iteration's sX reads done
        {
            const int kb = schunk * 8;
            sX[(kb + 0) * 18 + srow] = a.x;
            sX[(kb + 1) * 18 + srow] = a.y;
            sX[(kb + 2) * 18 + srow] = a.z;
            sX[(kb + 3) * 18 + srow] = a.w;
            sX[(kb + 4) * 18 + srow] = b.x;
            sX[(kb + 5) * 18 + srow] = b.y;
            sX[(kb + 6) * 18 + srow] = b.z;
            sX[(kb + 7) * 18 + srow] = b.w;
            if (schunk == 0) sN2[srow] = ss;
        }
        __syncthreads();

        float acc0[4] = {0.f, 0.f, 0.f, 0.f}, acc1[4] = {0.f, 0.f, 0.f, 0.f};
#pragma unroll 8
        for (int k = 0; k < 128; ++k) {
            const float2 xab = *reinterpret_cast<const float2*>(&sX[k * 18 + wid * 4]);
            const float2 xcd = *reinterpret_cast<const float2*>(&sX[k * 18 + wid * 4 + 2]);
            const float2 w   = *reinterpret_cast<const float2*>(&sWT[k * 130 + l2]);
            acc0[0] = fmaf(xab.x, w.x, acc0[0]); acc1[0] = fmaf(xab.x, w.y, acc1[0]);
            acc0[1] = fmaf(xab.y, w.x, acc0[1]); acc1[1] = fmaf(xab.y, w.y, acc1[1]);
            acc0[2] = fmaf(xcd.x, w.x, acc0[2]); acc1[2] = fmaf(xcd.x, w.y, acc1[2]);
            acc0[3] = fmaf(xcd.y, w.x, acc0[3]); acc1[3] = fmaf(xcd.y, w.y, acc1[3]);
        }

#pragma unroll
        for (int r = 0; r < 4; ++r) {
            const int row = base + wid * 4 + r;
            float m0 = acc0[r], m1 = acc1[r];        // raw = x @ W^T
            const float n2 = sN2[wid * 4 + r];
            const float n = fmaxf(sqrtf(n2), MIN_NORM);
            float sc = 1.f;
            if (PRELUDE) {                           // encode proj(expmap0(x)) as scalar
                sc = tanh_c(n) / n;
                sc *= proj_factor(sc * sc * n2);
            }
            const float xn = fmaxf(sc * n, MIN_NORM);
            const float rawn2 = wave_sum(m0 * m0 + m1 * m1);
            const float mxn = fmaxf(sc * sqrtf(rawn2), MIN_NORM);
            const float s = tanh_c(mxn / xn * artanh_c(xn));
            const float scl = (s * sc) / mxn;        // applies to raw
            m0 *= scl; m1 *= scl;
            float m2 = rawn2 * scl * scl;
            const float f = proj_factor(m2);
            m0 *= f; m1 *= f; m2 *= f * f;

            const float xy = wave_sum(m0 * yb0 + m1 * yb1);
            const float cx = 1.f + 2.f * xy + y2;
            const float cy = 1.f - m2;
            const float den = fmaxf(1.f + 2.f * xy + m2 * y2, MIN_NORM);
            float o0 = (cx * m0 + cy * yb0) / den;
            float o1 = (cx * m1 + cy * yb1) / den;

            float on2 = wave_sum(o0 * o0 + o1 * o1);
            const float f2 = proj_factor(on2);
            o0 *= f2; o1 *= f2; on2 *= f2 * f2;
            const float onn = fmaxf(sqrtf(on2), MIN_NORM);
            const float sl = artanh_c(onn) / onn;    // logmap0 (start of hyp_agg)
            if (row < n_rows)
                *reinterpret_cast<float2*>(&xtan[(size_t)row * 128 + l2]) =
                    make_float2(o0 * sl, o1 * sl);
        }
    }
}

// ---------------- gather aggregate + fused hyp_act ----------------
__global__ __launch_bounds__(256)
void gather_act(const float* __restrict__ xtan, const int* __restrict__ ptr,
                const uint2* __restrict__ epair, float* __restrict__ out, int n_rows) {
    const int v = blockIdx.x * 4 + (threadIdx.x >> 6);
    if (v >= n_rows) return;
    const int lane = threadIdx.x & 63, l2 = lane << 1;
    const int beg = ptr[v], end = ptr[v + 1];
    float a0 = 0.f, a1 = 0.f;
    int i = beg;
    for (; i + 1 < end; i += 2) {
        const uint2 p0 = epair[i], p1 = epair[i + 1];
        const float2 x0 = *reinterpret_cast<const float2*>(&xtan[(size_t)p0.x * 128 + l2]);
        const float2 x1 = *reinterpret_cast<const float2*>(&xtan[(size_t)p1.x * 128 + l2]);
        const float w0 = __uint_as_float(p0.y), w1 = __uint_as_float(p1.y);
        a0 = fmaf(w0, x0.x, a0); a1 = fmaf(w0, x0.y, a1);
        a0 = fmaf(w1, x1.x, a0); a1 = fmaf(w1, x1.y, a1);
    }
    if (i < end) {
        const uint2 p = epair[i];
        const float2 xv = *reinterpret_cast<const float2*>(&xtan[(size_t)p.x * 128 + l2]);
        const float w = __uint_as_float(p.y);
        a0 = fmaf(w, xv.x, a0); a1 = fmaf(w, xv.y, a1);
    }

    // h = proj(expmap0(agg)); xt = relu(logmap0(h)); out = proj(expmap0(xt))
    float n2 = wave_sum(a0 * a0 + a1 * a1);
    float n = fmaxf(sqrtf(n2), MIN_NORM);
    float sc = tanh_c(n) / n;
    float hn2 = sc * sc * n2;
    float f = proj_factor(hn2);
    sc *= f; hn2 *= f * f;
    float h0 = a0 * sc, h1 = a1 * sc;
    float hn = fmaxf(sqrtf(hn2), MIN_NORM);
    float sl = artanh_c(hn) / hn;
    float x0 = fmaxf(h0 * sl, 0.f), x1 = fmaxf(h1 * sl, 0.f);
    float n2b = wave_sum(x0 * x0 + x1 * x1);
    float nb = fmaxf(sqrtf(n2b), MIN_NORM);
    float scb = tanh_c(nb) / nb;
    scb *= proj_factor(scb * scb * n2b);
    *reinterpret_cast<float2*>(&out[(size_t)v * 128 + l2]) =
        make_float2(x0 * scb, x1 * scb);
}

// ---------------- fallback (R1 atomic path) ----------------
__global__ __launch_bounds__(256)
void agg_edges(const float* __restrict__ xtan, const int* __restrict__ src,
               const int* __restrict__ dst, const float* __restrict__ ew,
               float* __restrict__ agg, int n_edges) {
    int gt = blockIdx.x * blockDim.x + threadIdx.x;
    int e = gt >> 5;
    if (e >= n_edges) return;
    int c = (gt & 31) << 2;
    int sN = src[e], dN = dst[e];
    float w = ew[e];
    const float4 v = *reinterpret_cast<const float4*>(&xtan[(size_t)sN * 128 + c]);
    float* ap = &agg[(size_t)dN * 128 + c];
    atomicAdd(ap + 0, w * v.x);
    atomicAdd(ap + 1, w * v.y);
    atomicAdd(ap + 2, w * v.z);
    atomicAdd(ap + 3, w * v.w);
}

__global__ __launch_bounds__(256)
void hyp_act_kernel(const float* __restrict__ in, float* __restrict__ out, int n_rows) {
    int row = blockIdx.x * 4 + (threadIdx.x >> 6);
    if (row >= n_rows) return;
    int lane = threadIdx.x & 63;
    int l2 = lane << 1;
    const float2 v = *reinterpret_cast<const float2*>(&in[(size_t)row * 128 + l2]);
    float a0 = v.x, a1 = v.y;
    float n2 = wave_sum(a0 * a0 + a1 * a1);
    float n = fmaxf(sqrtf(n2), MIN_NORM);
    float sc = tanh_c(n) / n;
    float hn2 = sc * sc * n2;
    float f = proj_factor(hn2);
    sc *= f; hn2 *= f * f;
    float h0 = a0 * sc, h1 = a1 * sc;
    float hn = fmaxf(sqrtf(hn2), MIN_NORM);
    float sl = artanh_c(hn) / hn;
    float x0 = fmaxf(h0 * sl, 0.f), x1 = fmaxf(h1 * sl, 0.f);
    float n2b = wave_sum(x0 * x0 + x1 * x1);
    float nb = fmaxf(sqrtf(n2b), MIN_NORM);
    float scb = tanh_c(nb) / nb;
    scb *= proj_factor(scb * scb * n2b);
    *reinterpret_cast<float2*>(&out[(size_t)row * 128 + l2]) =
        make_float2(x0 * scb, x1 * scb);
}

extern "C" void kernel_launch(void* const* d_in, const int* in_sizes, int n_in,
                              void* d_out, int out_size, void* d_ws, size_t ws_size,
                              hipStream_t stream) {
    const float* x   = (const float*)d_in[0];
    const int*   src = (const int*)d_in[1];
    const int*   dst = (const int*)d_in[2];
    const float* ew  = (const float*)d_in[3];
    const float* W1  = (const float*)d_in[4];
    const float* b1  = (const float*)d_in[5];
    const float* W2  = (const float*)d_in[6];
    const float* b2  = (const float*)d_in[7];

    const int N = in_sizes[0] / 128;
    const int E = in_sizes[1];
    float* fout = (float*)d_out;

    const size_t need = (size_t)N * 128 * 4        // nbuf (16B-aligned at base)
                      + (size_t)E * 8              // epair
                      + ((size_t)(N + 1) + N + N + 512) * 4
                      + 256 * 4;                   // hb1/hb2

    if (ws_size >= need) {
        float* nbuf  = (float*)d_ws;
        uint2* epair = (uint2*)(nbuf + (size_t)N * 128);
        int* ptr     = (int*)(epair + E);
        int* cnt     = ptr + (N + 1);
        int* cursor  = cnt + N;
        int* bsum    = cursor + N;
        int* bscan   = bsum + 256;
        float* hb1   = (float*)(bscan + 256);
        float* hb2   = hb1 + 128;

        const int nbE = (E + 255) / 256;
        const int nbN = (N + 255) / 256;

        bias_kernel<<<1, 64, 0, stream>>>(b1, b2, hb1, hb2);

        // build CSR by dst (graph reused by both layers)
        hipMemsetAsync(cnt, 0, (size_t)N * 4, stream);
        hist_kernel<<<nbE, 256, 0, stream>>>(dst, cnt, E);
        scan1<<<nbN, 256, 0, stream>>>(cnt, ptr, bsum, N);
        scan2<<<1, 256, 0, stream>>>(bsum, bscan, nbN);
        scan3<<<nbN, 256, 0, stream>>>(bscan, ptr, cursor, N, E);
        scatter_kernel<<<nbE, 256, 0, stream>>>(src, dst, ew, cursor, epair, E);

        // layer 1 (x_tan1 in d_out)
        hyp_linear_tan<true><<<512, 256, 0, stream>>>(x, W1, hb1, fout, N);
        gather_act<<<(N + 3) / 4, 256, 0, stream>>>(fout, ptr, epair, nbuf, N);
        // layer 2 (x_tan2 in-place in nbuf; final in d_out)
        hyp_linear_tan<false><<<512, 256, 0, stream>>>(nbuf, W2, hb2, nbuf, N);
        gather_act<<<(N + 3) / 4, 256, 0, stream>>>(nbuf, ptr, epair, fout, N);
    } else {
        // fallback: R1 atomic-scatter path
        float* nbuf = (float*)d_ws;
        float* hb1  = nbuf + (size_t)N * 128;
        float* hb2  = hb1 + 128;
        const size_t node_bytes = (size_t)N * 128 * sizeof(float);
        const int agg_blocks = (int)(((size_t)E * 32 + 255) / 256);
        const int row_blocks = (N + 3) / 4;

        bias_kernel<<<1, 64, 0, stream>>>(b1, b2, hb1, hb2);
        hyp_linear_tan<true><<<512, 256, 0, stream>>>(x, W1, hb1, fout, N);
        hipMemsetAsync(nbuf, 0, node_bytes, stream);
        agg_edges<<<agg_blocks, 256, 0, stream>>>(fout, src, dst, ew, nbuf, E);
        hyp_act_kernel<<<row_blocks, 256, 0, stream>>>(nbuf, nbuf, N);
        hyp_linear_tan<false><<<512, 256, 0, stream>>>(nbuf, W2, hb2, nbuf, N);
        hipMemsetAsync(fout, 0, node_bytes, stream);
        agg_edges<<<agg_blocks, 256, 0, stream>>>(nbuf, src, dst, ew, fout, E);
        hyp_act_kernel<<<row_blocks, 256, 0, stream>>>(fout, fout, N);
    }
}

// Round 5
// 384.203 us; speedup vs baseline: 5.4502x; 1.0002x over previous
//
#include <hip/hip_runtime.h>
#include <math.h>

#define MIN_NORM 1e-15f
#define MAXNORM  0.996f          /* (1 - 4e-3)/sqrt(c), c=1 */
#define ARTANH_CLIP 0.99999988f  /* float(1.0 - 1e-7) */

__device__ __forceinline__ float wave_sum(float v) {
#pragma unroll
    for (int off = 32; off > 0; off >>= 1) v += __shfl_xor(v, off, 64);
    return v;
}

__device__ __forceinline__ float artanh_c(float x) {
    x = fminf(fmaxf(x, -ARTANH_CLIP), ARTANH_CLIP);
    return 0.5f * (log1pf(x) - log1pf(-x));
}

__device__ __forceinline__ float tanh_c(float x) {
    return tanhf(fminf(fmaxf(x, -15.f), 15.f));
}

__device__ __forceinline__ float proj_factor(float n2) {
    float n = fmaxf(sqrtf(n2), MIN_NORM);
    return (n > MAXNORM) ? (MAXNORM / n) : 1.f;
}

// hyp_bias = proj(expmap0(b, c), c) for both layers. 1 block x 64 threads.
__global__ void bias_kernel(const float* __restrict__ b1, const float* __restrict__ b2,
                            float* __restrict__ hb1, float* __restrict__ hb2) {
    int lane = threadIdx.x;
#pragma unroll
    for (int j = 0; j < 2; ++j) {
        const float* b = j ? b2 : b1;
        float* hb = j ? hb2 : hb1;
        float v0 = b[lane], v1 = b[lane + 64];
        float n2 = wave_sum(v0 * v0 + v1 * v1);
        float n = fmaxf(sqrtf(n2), MIN_NORM);
        float sc = tanh_c(n) / n;
        sc *= proj_factor(sc * sc * n2);
        hb[lane] = v0 * sc;
        hb[lane + 64] = v1 * sc;
    }
}

// ---------------- CSR build ----------------

__global__ void hist_kernel(const int* __restrict__ dst, int* __restrict__ cnt, int E) {
    int e = blockIdx.x * blockDim.x + threadIdx.x;
    if (e < E) atomicAdd(&cnt[dst[e]], 1);
}

__global__ void scan1(const int* __restrict__ cnt, int* __restrict__ ptr,
                      int* __restrict__ bsum, int N) {
    __shared__ int s[256];
    const int t = threadIdx.x;
    const int i = blockIdx.x * 256 + t;
    int v = (i < N) ? cnt[i] : 0;
    s[t] = v;
    __syncthreads();
#pragma unroll
    for (int off = 1; off < 256; off <<= 1) {
        int add = (t >= off) ? s[t - off] : 0;
        __syncthreads();
        s[t] += add;
        __syncthreads();
    }
    if (i < N) ptr[i] = s[t] - v;          // exclusive within block
    if (t == 255) bsum[blockIdx.x] = s[255];
}

__global__ void scan2(const int* __restrict__ bsum, int* __restrict__ bscan, int nb) {
    __shared__ int s[256];
    const int t = threadIdx.x;
    int v = (t < nb) ? bsum[t] : 0;
    s[t] = v;
    __syncthreads();
#pragma unroll
    for (int off = 1; off < 256; off <<= 1) {
        int add = (t >= off) ? s[t - off] : 0;
        __syncthreads();
        s[t] += add;
        __syncthreads();
    }
    bscan[t] = s[t] - v;                   // exclusive block offsets
}

__global__ void scan3(const int* __restrict__ bscan, int* __restrict__ ptr,
                      int* __restrict__ cursor, int N, int E) {
    const int i = blockIdx.x * blockDim.x + threadIdx.x;
    if (i < N) {
        const int p = ptr[i] + bscan[i >> 8];
        ptr[i] = p;
        cursor[i] = p;
    }
    if (i == 0) ptr[N] = E;
}

__global__ void scatter_kernel(const int* __restrict__ src, const int* __restrict__ dst,
                               const float* __restrict__ ew, int* __restrict__ cursor,
                               uint2* __restrict__ epair, int E) {
    int e = blockIdx.x * blockDim.x + threadIdx.x;
    if (e >= E) return;
    int pos = atomicAdd(&cursor[dst[e]], 1);
    epair[pos] = make_uint2((unsigned)src[e], __float_as_uint(ew[e]));
}

// ---------------- fused linear (encode? -> mobius matvec -> +bias -> proj -> logmap0) ----------------
// 4 rows per wave, 16 rows per block iteration. x staged in LDS column-major
// (stride 18 floats: keeps 8B alignment for b64 reads, bounds write conflicts).
template <bool PRELUDE>
__global__ __launch_bounds__(256)
void hyp_linear_tan(const float* __restrict__ xin, const float* __restrict__ W,
                    const float* __restrict__ hb, float* __restrict__ xtan, int n_rows) {
    __shared__ float sWT[128 * 130];   // [k][o], pad 130
    __shared__ float sX[128 * 18];     // [k][row 0..15], stride 18
    __shared__ float sN2[16];
    __shared__ float sHB[128];
    __shared__ float sHB2;

    const int tid = threadIdx.x;
    for (int idx = tid; idx < 128 * 128; idx += 256) {
        int o = idx >> 7, k = idx & 127;
        sWT[k * 130 + o] = W[idx];     // transpose: [in][out]
    }
    if (tid < 128) sHB[tid] = hb[tid];
    __syncthreads();
    if (tid < 64) {
        float v0 = sHB[tid], v1 = sHB[tid + 64];
        float s = wave_sum(v0 * v0 + v1 * v1);
        if (tid == 0) sHB2 = s;
    }
    __syncthreads();

    const int wid = tid >> 6, lane = tid & 63, l2 = lane << 1;
    const float y2 = sHB2;
    const float yb0 = sHB[l2], yb1 = sHB[l2 + 1];
    const int srow = tid >> 4;         // 0..15: staging row
    const int schunk = tid & 15;       // 8-float chunk within row

    for (int base = blockIdx.x * 16; base < n_rows; base += gridDim.x * 16) {
        const int grow = base + srow;
        float4 a = make_float4(0.f, 0.f, 0.f, 0.f), b = a;
        if (grow < n_rows) {
            const float* xr = xin + (size_t)grow * 128 + schunk * 8;
            a = *reinterpret_cast<const float4*>(xr);
            b = *reinterpret_cast<const float4*>(xr + 4);
        }
        float ss = a.x * a.x + a.y * a.y + a.z * a.z + a.w * a.w
                 + b.x * b.x + b.y * b.y + b.z * b.z + b.w * b.w;
#pragma unroll
        for (int off = 1; off < 16; off <<= 1) ss += __shfl_xor(ss, off, 64);

        __syncthreads();               // previous iteration's sX reads done
        {
            const int kb = schunk * 8;
            sX[(kb + 0) * 18 + srow] = a.x;
            sX[(kb + 1) * 18 + srow] = a.y;
            sX[(kb + 2) * 18 + srow] = a.z;
            sX[(kb + 3) * 18 + srow] = a.w;
            sX[(kb + 4) * 18 + srow] = b.x;
            sX[(kb + 5) * 18 + srow] = b.y;
            sX[(kb + 6) * 18 + srow] = b.z;
            sX[(kb + 7) * 18 + srow] = b.w;
            if (schunk == 0) sN2[srow] = ss;
        }
        __syncthreads();

        float acc0[4] = {0.f, 0.f, 0.f, 0.f}, acc1[4] = {0.f, 0.f, 0.f, 0.f};
#pragma unroll 8
        for (int k = 0; k < 128; ++k) {
            const float2 xab = *reinterpret_cast<const float2*>(&sX[k * 18 + wid * 4]);
            const float2 xcd = *reinterpret_cast<const float2*>(&sX[k * 18 + wid * 4 + 2]);
            const float2 w   = *reinterpret_cast<const float2*>(&sWT[k * 130 + l2]);
            acc0[0] = fmaf(xab.x, w.x, acc0[0]); acc1[0] = fmaf(xab.x, w.y, acc1[0]);
            acc0[1] = fmaf(xab.y, w.x, acc0[1]); acc1[1] = fmaf(xab.y, w.y, acc1[1]);
            acc0[2] = fmaf(xcd.x, w.x, acc0[2]); acc1[2] = fmaf(xcd.x, w.y, acc1[2]);
            acc0[3] = fmaf(xcd.y, w.x, acc0[3]); acc1[3] = fmaf(xcd.y, w.y, acc1[3]);
        }

#pragma unroll
        for (int r = 0; r < 4; ++r) {
            const int row = base + wid * 4 + r;
            float m0 = acc0[r], m1 = acc1[r];        // raw = x @ W^T
            const float n2 = sN2[wid * 4 + r];
            const float n = fmaxf(sqrtf(n2), MIN_NORM);
            float sc = 1.f;
            if (PRELUDE) {                           // encode proj(expmap0(x)) as scalar
                sc = tanh_c(n) / n;
                sc *= proj_factor(sc * sc * n2);
            }
            const float xn = fmaxf(sc * n, MIN_NORM);
            const float rawn2 = wave_sum(m0 * m0 + m1 * m1);
            const float mxn = fmaxf(sc * sqrtf(rawn2), MIN_NORM);
            const float s = tanh_c(mxn / xn * artanh_c(xn));
            const float scl = (s * sc) / mxn;        // applies to raw
            m0 *= scl; m1 *= scl;
            float m2 = rawn2 * scl * scl;
            const float f = proj_factor(m2);
            m0 *= f; m1 *= f; m2 *= f * f;

            const float xy = wave_sum(m0 * yb0 + m1 * yb1);
            const float cx = 1.f + 2.f * xy + y2;
            const float cy = 1.f - m2;
            const float den = fmaxf(1.f + 2.f * xy + m2 * y2, MIN_NORM);
            float o0 = (cx * m0 + cy * yb0) / den;
            float o1 = (cx * m1 + cy * yb1) / den;

            float on2 = wave_sum(o0 * o0 + o1 * o1);
            const float f2 = proj_factor(on2);
            o0 *= f2; o1 *= f2; on2 *= f2 * f2;
            const float onn = fmaxf(sqrtf(on2), MIN_NORM);
            const float sl = artanh_c(onn) / onn;    // logmap0 (start of hyp_agg)
            if (row < n_rows)
                *reinterpret_cast<float2*>(&xtan[(size_t)row * 128 + l2]) =
                    make_float2(o0 * sl, o1 * sl);
        }
    }
}

// ---------------- gather aggregate + fused hyp_act ----------------
__global__ __launch_bounds__(256)
void gather_act(const float* __restrict__ xtan, const int* __restrict__ ptr,
                const uint2* __restrict__ epair, float* __restrict__ out, int n_rows) {
    const int v = blockIdx.x * 4 + (threadIdx.x >> 6);
    if (v >= n_rows) return;
    const int lane = threadIdx.x & 63, l2 = lane << 1;
    const int beg = ptr[v], end = ptr[v + 1];
    float a0 = 0.f, a1 = 0.f;
    int i = beg;
    for (; i + 1 < end; i += 2) {
        const uint2 p0 = epair[i], p1 = epair[i + 1];
        const float2 x0 = *reinterpret_cast<const float2*>(&xtan[(size_t)p0.x * 128 + l2]);
        const float2 x1 = *reinterpret_cast<const float2*>(&xtan[(size_t)p1.x * 128 + l2]);
        const float w0 = __uint_as_float(p0.y), w1 = __uint_as_float(p1.y);
        a0 = fmaf(w0, x0.x, a0); a1 = fmaf(w0, x0.y, a1);
        a0 = fmaf(w1, x1.x, a0); a1 = fmaf(w1, x1.y, a1);
    }
    if (i < end) {
        const uint2 p = epair[i];
        const float2 xv = *reinterpret_cast<const float2*>(&xtan[(size_t)p.x * 128 + l2]);
        const float w = __uint_as_float(p.y);
        a0 = fmaf(w, xv.x, a0); a1 = fmaf(w, xv.y, a1);
    }

    // h = proj(expmap0(agg)); xt = relu(logmap0(h)); out = proj(expmap0(xt))
    float n2 = wave_sum(a0 * a0 + a1 * a1);
    float n = fmaxf(sqrtf(n2), MIN_NORM);
    float sc = tanh_c(n) / n;
    float hn2 = sc * sc * n2;
    float f = proj_factor(hn2);
    sc *= f; hn2 *= f * f;
    float h0 = a0 * sc, h1 = a1 * sc;
    float hn = fmaxf(sqrtf(hn2), MIN_NORM);
    float sl = artanh_c(hn) / hn;
    float x0 = fmaxf(h0 * sl, 0.f), x1 = fmaxf(h1 * sl, 0.f);
    float n2b = wave_sum(x0 * x0 + x1 * x1);
    float nb = fmaxf(sqrtf(n2b), MIN_NORM);
    float scb = tanh_c(nb) / nb;
    scb *= proj_factor(scb * scb * n2b);
    *reinterpret_cast<float2*>(&out[(size_t)v * 128 + l2]) =
        make_float2(x0 * scb, x1 * scb);
}

// ---------------- fallback (R1 atomic path) ----------------
__global__ __launch_bounds__(256)
void agg_edges(const float* __restrict__ xtan, const int* __restrict__ src,
               const int* __restrict__ dst, const float* __restrict__ ew,
               float* __restrict__ agg, int n_edges) {
    int gt = blockIdx.x * blockDim.x + threadIdx.x;
    int e = gt >> 5;
    if (e >= n_edges) return;
    int c = (gt & 31) << 2;
    int sN = src[e], dN = dst[e];
    float w = ew[e];
    const float4 v = *reinterpret_cast<const float4*>(&xtan[(size_t)sN * 128 + c]);
    float* ap = &agg[(size_t)dN * 128 + c];
    atomicAdd(ap + 0, w * v.x);
    atomicAdd(ap + 1, w * v.y);
    atomicAdd(ap + 2, w * v.z);
    atomicAdd(ap + 3, w * v.w);
}

__global__ __launch_bounds__(256)
void hyp_act_kernel(const float* __restrict__ in, float* __restrict__ out, int n_rows) {
    int row = blockIdx.x * 4 + (threadIdx.x >> 6);
    if (row >= n_rows) return;
    int lane = threadIdx.x & 63;
    int l2 = lane << 1;
    const float2 v = *reinterpret_cast<const float2*>(&in[(size_t)row * 128 + l2]);
    float a0 = v.x, a1 = v.y;
    float n2 = wave_sum(a0 * a0 + a1 * a1);
    float n = fmaxf(sqrtf(n2), MIN_NORM);
    float sc = tanh_c(n) / n;
    float hn2 = sc * sc * n2;
    float f = proj_factor(hn2);
    sc *= f; hn2 *= f * f;
    float h0 = a0 * sc, h1 = a1 * sc;
    float hn = fmaxf(sqrtf(hn2), MIN_NORM);
    float sl = artanh_c(hn) / hn;
    float x0 = fmaxf(h0 * sl, 0.f), x1 = fmaxf(h1 * sl, 0.f);
    float n2b = wave_sum(x0 * x0 + x1 * x1);
    float nb = fmaxf(sqrtf(n2b), MIN_NORM);
    float scb = tanh_c(nb) / nb;
    scb *= proj_factor(scb * scb * n2b);
    *reinterpret_cast<float2*>(&out[(size_t)row * 128 + l2]) =
        make_float2(x0 * scb, x1 * scb);
}

extern "C" void kernel_launch(void* const* d_in, const int* in_sizes, int n_in,
                              void* d_out, int out_size, void* d_ws, size_t ws_size,
                              hipStream_t stream) {
    const float* x   = (const float*)d_in[0];
    const int*   src = (const int*)d_in[1];
    const int*   dst = (const int*)d_in[2];
    const float* ew  = (const float*)d_in[3];
    const float* W1  = (const float*)d_in[4];
    const float* b1  = (const float*)d_in[5];
    const float* W2  = (const float*)d_in[6];
    const float* b2  = (const float*)d_in[7];

    const int N = in_sizes[0] / 128;
    const int E = in_sizes[1];
    float* fout = (float*)d_out;

    const size_t need = (size_t)N * 128 * 4        // nbuf (16B-aligned at base)
                      + (size_t)E * 8              // epair
                      + ((size_t)(N + 1) + N + N + 512) * 4
                      + 256 * 4;                   // hb1/hb2

    if (ws_size >= need) {
        float* nbuf  = (float*)d_ws;
        uint2* epair = (uint2*)(nbuf + (size_t)N * 128);
        int* ptr     = (int*)(epair + E);
        int* cnt     = ptr + (N + 1);
        int* cursor  = cnt + N;
        int* bsum    = cursor + N;
        int* bscan   = bsum + 256;
        float* hb1   = (float*)(bscan + 256);
        float* hb2   = hb1 + 128;

        const int nbE = (E + 255) / 256;
        const int nbN = (N + 255) / 256;

        bias_kernel<<<1, 64, 0, stream>>>(b1, b2, hb1, hb2);

        // build CSR by dst (graph reused by both layers)
        hipMemsetAsync(cnt, 0, (size_t)N * 4, stream);
        hist_kernel<<<nbE, 256, 0, stream>>>(dst, cnt, E);
        scan1<<<nbN, 256, 0, stream>>>(cnt, ptr, bsum, N);
        scan2<<<1, 256, 0, stream>>>(bsum, bscan, nbN);
        scan3<<<nbN, 256, 0, stream>>>(bscan, ptr, cursor, N, E);
        scatter_kernel<<<nbE, 256, 0, stream>>>(src, dst, ew, cursor, epair, E);

        // layer 1 (x_tan1 in d_out)
        hyp_linear_tan<true><<<512, 256, 0, stream>>>(x, W1, hb1, fout, N);
        gather_act<<<(N + 3) / 4, 256, 0, stream>>>(fout, ptr, epair, nbuf, N);
        // layer 2 (x_tan2 in-place in nbuf; final in d_out)
        hyp_linear_tan<false><<<512, 256, 0, stream>>>(nbuf, W2, hb2, nbuf, N);
        gather_act<<<(N + 3) / 4, 256, 0, stream>>>(nbuf, ptr, epair, fout, N);
    } else {
        // fallback: R1 atomic-scatter path
        float* nbuf = (float*)d_ws;
        float* hb1  = nbuf + (size_t)N * 128;
        float* hb2  = hb1 + 128;
        const size_t node_bytes = (size_t)N * 128 * sizeof(float);
        const int agg_blocks = (int)(((size_t)E * 32 + 255) / 256);
        const int row_blocks = (N + 3) / 4;

        bias_kernel<<<1, 64, 0, stream>>>(b1, b2, hb1, hb2);
        hyp_linear_tan<true><<<512, 256, 0, stream>>>(x, W1, hb1, fout, N);
        hipMemsetAsync(nbuf, 0, node_bytes, stream);
        agg_edges<<<agg_blocks, 256, 0, stream>>>(fout, src, dst, ew, nbuf, E);
        hyp_act_kernel<<<row_blocks, 256, 0, stream>>>(nbuf, nbuf, N);
        hyp_linear_tan<false><<<512, 256, 0, stream>>>(nbuf, W2, hb2, nbuf, N);
        hipMemsetAsync(fout, 0, node_bytes, stream);
        agg_edges<<<agg_blocks, 256, 0, stream>>>(nbuf, src, dst, ew, fout, E);
        hyp_act_kernel<<<row_blocks, 256, 0, stream>>>(fout, fout, N);
    }
}

// Round 6
// 295.821 us; speedup vs baseline: 7.0785x; 1.2988x over previous
//
#include <hip/hip_runtime.h>
#include <math.h>

#define MIN_NORM 1e-15f
#define MAXNORM  0.996f          /* (1 - 4e-3)/sqrt(c), c=1 */
#define ARTANH_CLIP 0.99999988f  /* float(1.0 - 1e-7) */

typedef __bf16 bf16x8 __attribute__((ext_vector_type(8)));
typedef float  f32x4  __attribute__((ext_vector_type(4)));

union FragU { ushort u[8]; uint4 q; bf16x8 v; };

__device__ __forceinline__ float wave_sum(float v) {
#pragma unroll
    for (int off = 32; off > 0; off >>= 1) v += __shfl_xor(v, off, 64);
    return v;
}

__device__ __forceinline__ float artanh_c(float x) {
    x = fminf(fmaxf(x, -ARTANH_CLIP), ARTANH_CLIP);
    return 0.5f * (log1pf(x) - log1pf(-x));
}

__device__ __forceinline__ float tanh_c(float x) {
    return tanhf(fminf(fmaxf(x, -15.f), 15.f));
}

__device__ __forceinline__ float proj_factor(float n2) {
    float n = fmaxf(sqrtf(n2), MIN_NORM);
    return (n > MAXNORM) ? (MAXNORM / n) : 1.f;
}

__device__ __forceinline__ unsigned short f2bf(float f) {   // RNE
    unsigned u = __float_as_uint(f);
    return (unsigned short)((u + 0x7fffu + ((u >> 16) & 1u)) >> 16);
}
__device__ __forceinline__ float bf2f(unsigned short h) {
    return __uint_as_float((unsigned)h << 16);
}

__device__ __forceinline__ void red16_f4(float4& v) {
#pragma unroll
    for (int off = 1; off < 16; off <<= 1) {
        v.x += __shfl_xor(v.x, off, 64);
        v.y += __shfl_xor(v.y, off, 64);
        v.z += __shfl_xor(v.z, off, 64);
        v.w += __shfl_xor(v.w, off, 64);
    }
}

// hyp_bias = proj(expmap0(b, c), c) for both layers. 1 block x 64 threads.
__global__ void bias_kernel(const float* __restrict__ b1, const float* __restrict__ b2,
                            float* __restrict__ hb1, float* __restrict__ hb2) {
    int lane = threadIdx.x;
#pragma unroll
    for (int j = 0; j < 2; ++j) {
        const float* b = j ? b2 : b1;
        float* hb = j ? hb2 : hb1;
        float v0 = b[lane], v1 = b[lane + 64];
        float n2 = wave_sum(v0 * v0 + v1 * v1);
        float n = fmaxf(sqrtf(n2), MIN_NORM);
        float sc = tanh_c(n) / n;
        sc *= proj_factor(sc * sc * n2);
        hb[lane] = v0 * sc;
        hb[lane + 64] = v1 * sc;
    }
}

// ---------------- CSR build ----------------

__global__ void hist_kernel(const int* __restrict__ dst, int* __restrict__ cnt, int E) {
    int e = blockIdx.x * blockDim.x + threadIdx.x;
    if (e < E) atomicAdd(&cnt[dst[e]], 1);
}

__global__ void scan1(const int* __restrict__ cnt, int* __restrict__ ptr,
                      int* __restrict__ bsum, int N) {
    __shared__ int s[256];
    const int t = threadIdx.x;
    const int i = blockIdx.x * 256 + t;
    int v = (i < N) ? cnt[i] : 0;
    s[t] = v;
    __syncthreads();
#pragma unroll
    for (int off = 1; off < 256; off <<= 1) {
        int add = (t >= off) ? s[t - off] : 0;
        __syncthreads();
        s[t] += add;
        __syncthreads();
    }
    if (i < N) ptr[i] = s[t] - v;
    if (t == 255) bsum[blockIdx.x] = s[255];
}

__global__ void scan2(const int* __restrict__ bsum, int* __restrict__ bscan, int nb) {
    __shared__ int s[256];
    const int t = threadIdx.x;
    int v = (t < nb) ? bsum[t] : 0;
    s[t] = v;
    __syncthreads();
#pragma unroll
    for (int off = 1; off < 256; off <<= 1) {
        int add = (t >= off) ? s[t - off] : 0;
        __syncthreads();
        s[t] += add;
        __syncthreads();
    }
    bscan[t] = s[t] - v;
}

__global__ void scan3(const int* __restrict__ bscan, int* __restrict__ ptr,
                      int* __restrict__ cursor, int N, int E) {
    const int i = blockIdx.x * blockDim.x + threadIdx.x;
    if (i < N) {
        const int p = ptr[i] + bscan[i >> 8];
        ptr[i] = p;
        cursor[i] = p;
    }
    if (i == 0) ptr[N] = E;
}

__global__ void scatter_kernel(const int* __restrict__ src, const int* __restrict__ dst,
                               const float* __restrict__ ew, int* __restrict__ cursor,
                               uint2* __restrict__ epair, int E) {
    int e = blockIdx.x * blockDim.x + threadIdx.x;
    if (e >= E) return;
    int pos = atomicAdd(&cursor[dst[e]], 1);
    epair[pos] = make_uint2((unsigned)src[e], __float_as_uint(ew[e]));
}

// ---------------- MFMA fused linear ----------------
// raw = x @ W^T via bf16x3 split (x_hi*W_hi + x_hi*W_lo + x_lo*W_hi), then
// f32 epilogue: [encode]->mobius scale->+bias->proj->logmap0. One wave = 16 rows.
// W_hi/W_lo in LDS, row stride 256B, XOR-swizzled (byte ^= (row&7)<<4) so the
// 16-lane B-frag column read is 2-way (free) instead of 16-way conflicted.
template <bool PRELUDE>
__global__ __launch_bounds__(256)
void hyp_linear_tan_mfma(const float* __restrict__ xin, const float* __restrict__ W,
                         const float* __restrict__ hb, float* __restrict__ xtan,
                         int n_rows) {
    __shared__ __align__(16) unsigned short sWhi[128 * 128];
    __shared__ __align__(16) unsigned short sWlo[128 * 128];

    const int tid = threadIdx.x;
    // stage W as bf16 hi/lo, swizzled
    for (int i = tid * 4; i < 128 * 128; i += 256 * 4) {
        const int row = i >> 7, col = i & 127;
        const float4 w4 = *reinterpret_cast<const float4*>(&W[i]);
        ushort4 h, l;
        h.x = f2bf(w4.x); l.x = f2bf(w4.x - bf2f(h.x));
        h.y = f2bf(w4.y); l.y = f2bf(w4.y - bf2f(h.y));
        h.z = f2bf(w4.z); l.z = f2bf(w4.z - bf2f(h.z));
        h.w = f2bf(w4.w); l.w = f2bf(w4.w - bf2f(h.w));
        const unsigned byte = (unsigned)((row << 8) + (col << 1)) ^ (unsigned)((row & 7) << 4);
        *reinterpret_cast<ushort4*>(reinterpret_cast<char*>(sWhi) + byte) = h;
        *reinterpret_cast<ushort4*>(reinterpret_cast<char*>(sWlo) + byte) = l;
    }
    __syncthreads();

    const int lane = tid & 63, wid = tid >> 6;
    const int r15 = lane & 15, g = lane >> 4;

    // bias fragment: yb[ct] = hb[16*ct + r15]; y2 = sum over 128 cols
    float yb[8];
    float y2p = 0.f;
#pragma unroll
    for (int t = 0; t < 8; ++t) { yb[t] = hb[t * 16 + r15]; y2p += yb[t] * yb[t]; }
    {
#pragma unroll
        for (int off = 1; off < 16; off <<= 1) y2p += __shfl_xor(y2p, off, 64);
    }
    const float y2 = y2p;

    const int tiles = (n_rows + 15) >> 4;
    const unsigned lswz = (unsigned)((r15 & 7) << 4);

    for (int tile = blockIdx.x * 4 + wid; tile < tiles; tile += gridDim.x * 4) {
        const int rowbase = tile << 4;
        const int myrow = rowbase + r15;
        const bool rok = (myrow < n_rows);
        const float* xr = xin + (size_t)myrow * 128 + g * 8;

        // load my 32 x-values (f32), build hi/lo bf16 A-frags, accumulate norm
        FragU ah[4], al[4];
        float ss = 0.f;
#pragma unroll
        for (int kc = 0; kc < 4; ++kc) {
            float4 xa = make_float4(0.f, 0.f, 0.f, 0.f), xb = xa;
            if (rok) {
                xa = *reinterpret_cast<const float4*>(xr + kc * 32);
                xb = *reinterpret_cast<const float4*>(xr + kc * 32 + 4);
            }
            ss += xa.x * xa.x + xa.y * xa.y + xa.z * xa.z + xa.w * xa.w
                + xb.x * xb.x + xb.y * xb.y + xb.z * xb.z + xb.w * xb.w;
            const float xv[8] = {xa.x, xa.y, xa.z, xa.w, xb.x, xb.y, xb.z, xb.w};
#pragma unroll
            for (int j = 0; j < 8; ++j) {
                const unsigned short hbit = f2bf(xv[j]);
                ah[kc].u[j] = hbit;
                al[kc].u[j] = f2bf(xv[j] - bf2f(hbit));
            }
        }
        ss += __shfl_xor(ss, 16, 64);
        ss += __shfl_xor(ss, 32, 64);   // n2 of row myrow (replicated x4)

        f32x4 acc[8];
#pragma unroll
        for (int ct = 0; ct < 8; ++ct) acc[ct] = (f32x4){0.f, 0.f, 0.f, 0.f};

#pragma unroll
        for (int kc = 0; kc < 4; ++kc) {
#pragma unroll
            for (int ct = 0; ct < 8; ++ct) {
                const unsigned byte =
                    ((unsigned)((ct << 12) + (r15 << 8) + (kc << 6) + (g << 4))) ^ lswz;
                FragU bh, bl;
                bh.q = *reinterpret_cast<const uint4*>(
                    reinterpret_cast<const char*>(sWhi) + byte);
                bl.q = *reinterpret_cast<const uint4*>(
                    reinterpret_cast<const char*>(sWlo) + byte);
                acc[ct] = __builtin_amdgcn_mfma_f32_16x16x32_bf16(ah[kc].v, bh.v, acc[ct], 0, 0, 0);
                acc[ct] = __builtin_amdgcn_mfma_f32_16x16x32_bf16(ah[kc].v, bl.v, acc[ct], 0, 0, 0);
                acc[ct] = __builtin_amdgcn_mfma_f32_16x16x32_bf16(al[kc].v, bh.v, acc[ct], 0, 0, 0);
            }
        }

        // ---- epilogue: lane holds rows 4g+reg (reg=0..3), cols 16ct+r15 ----
        float4 r2 = make_float4(0.f, 0.f, 0.f, 0.f);
#pragma unroll
        for (int ct = 0; ct < 8; ++ct) {
            r2.x += acc[ct][0] * acc[ct][0];
            r2.y += acc[ct][1] * acc[ct][1];
            r2.z += acc[ct][2] * acc[ct][2];
            r2.w += acc[ct][3] * acc[ct][3];
        }
        red16_f4(r2);   // rawn2 per reg-row

        float scl[4], m2a[4];
        const float rn2a[4] = {r2.x, r2.y, r2.z, r2.w};
#pragma unroll
        for (int reg = 0; reg < 4; ++reg) {
            const float n2v = __shfl(ss, 4 * g + reg, 64);   // input-row norm^2
            const float rn2 = rn2a[reg];
            const float n = fmaxf(sqrtf(n2v), MIN_NORM);
            float sc = 1.f;
            if (PRELUDE) {                 // encode proj(expmap0(x)) as row scalar
                sc = tanh_c(n) / n;
                sc *= proj_factor(sc * sc * n2v);
            }
            const float xn = fmaxf(sc * n, MIN_NORM);
            const float mxn = fmaxf(sc * sqrtf(rn2), MIN_NORM);
            const float s = tanh_c(mxn / xn * artanh_c(xn));
            float sl0 = (s * sc) / mxn;    // applies to raw
            float m2 = rn2 * sl0 * sl0;
            const float f = proj_factor(m2);
            scl[reg] = sl0 * f;
            m2a[reg] = m2 * f * f;
        }

        float4 xy = make_float4(0.f, 0.f, 0.f, 0.f);
#pragma unroll
        for (int ct = 0; ct < 8; ++ct) {
            acc[ct][0] *= scl[0]; acc[ct][1] *= scl[1];
            acc[ct][2] *= scl[2]; acc[ct][3] *= scl[3];
            xy.x += acc[ct][0] * yb[ct];
            xy.y += acc[ct][1] * yb[ct];
            xy.z += acc[ct][2] * yb[ct];
            xy.w += acc[ct][3] * yb[ct];
        }
        red16_f4(xy);

        float cx[4], cy[4], rdn[4];
        const float xya[4] = {xy.x, xy.y, xy.z, xy.w};
#pragma unroll
        for (int reg = 0; reg < 4; ++reg) {
            cx[reg] = 1.f + 2.f * xya[reg] + y2;
            cy[reg] = 1.f - m2a[reg];
            rdn[reg] = 1.f / fmaxf(1.f + 2.f * xya[reg] + m2a[reg] * y2, MIN_NORM);
        }

        float4 on2 = make_float4(0.f, 0.f, 0.f, 0.f);
#pragma unroll
        for (int ct = 0; ct < 8; ++ct) {
            acc[ct][0] = (cx[0] * acc[ct][0] + cy[0] * yb[ct]) * rdn[0];
            acc[ct][1] = (cx[1] * acc[ct][1] + cy[1] * yb[ct]) * rdn[1];
            acc[ct][2] = (cx[2] * acc[ct][2] + cy[2] * yb[ct]) * rdn[2];
            acc[ct][3] = (cx[3] * acc[ct][3] + cy[3] * yb[ct]) * rdn[3];
            on2.x += acc[ct][0] * acc[ct][0];
            on2.y += acc[ct][1] * acc[ct][1];
            on2.z += acc[ct][2] * acc[ct][2];
            on2.w += acc[ct][3] * acc[ct][3];
        }
        red16_f4(on2);

        float wsc[4];
        const float on2a[4] = {on2.x, on2.y, on2.z, on2.w};
#pragma unroll
        for (int reg = 0; reg < 4; ++reg) {
            const float f2 = proj_factor(on2a[reg]);
            const float v = on2a[reg] * f2 * f2;
            const float onn = fmaxf(sqrtf(v), MIN_NORM);
            wsc[reg] = f2 * artanh_c(onn) / onn;   // proj + logmap0 scale
        }

#pragma unroll
        for (int reg = 0; reg < 4; ++reg) {
            const int row = rowbase + 4 * g + reg;
            if (row < n_rows) {
                float* orow = xtan + (size_t)row * 128 + r15;
#pragma unroll
                for (int ct = 0; ct < 8; ++ct) orow[ct * 16] = acc[ct][reg] * wsc[reg];
            }
        }
    }
}

// ---------------- gather aggregate + fused hyp_act ----------------
__global__ __launch_bounds__(256)
void gather_act(const float* __restrict__ xtan, const int* __restrict__ ptr,
                const uint2* __restrict__ epair, float* __restrict__ out, int n_rows) {
    const int v = blockIdx.x * 4 + (threadIdx.x >> 6);
    if (v >= n_rows) return;
    const int lane = threadIdx.x & 63, l2 = lane << 1;
    const int beg = ptr[v], end = ptr[v + 1];
    float a0 = 0.f, a1 = 0.f;
    int i = beg;
    for (; i + 1 < end; i += 2) {
        const uint2 p0 = epair[i], p1 = epair[i + 1];
        const float2 x0 = *reinterpret_cast<const float2*>(&xtan[(size_t)p0.x * 128 + l2]);
        const float2 x1 = *reinterpret_cast<const float2*>(&xtan[(size_t)p1.x * 128 + l2]);
        const float w0 = __uint_as_float(p0.y), w1 = __uint_as_float(p1.y);
        a0 = fmaf(w0, x0.x, a0); a1 = fmaf(w0, x0.y, a1);
        a0 = fmaf(w1, x1.x, a0); a1 = fmaf(w1, x1.y, a1);
    }
    if (i < end) {
        const uint2 p = epair[i];
        const float2 xv = *reinterpret_cast<const float2*>(&xtan[(size_t)p.x * 128 + l2]);
        const float w = __uint_as_float(p.y);
        a0 = fmaf(w, xv.x, a0); a1 = fmaf(w, xv.y, a1);
    }

    float n2 = wave_sum(a0 * a0 + a1 * a1);
    float n = fmaxf(sqrtf(n2), MIN_NORM);
    float sc = tanh_c(n) / n;
    float hn2 = sc * sc * n2;
    float f = proj_factor(hn2);
    sc *= f; hn2 *= f * f;
    float h0 = a0 * sc, h1 = a1 * sc;
    float hn = fmaxf(sqrtf(hn2), MIN_NORM);
    float sl = artanh_c(hn) / hn;
    float x0 = fmaxf(h0 * sl, 0.f), x1 = fmaxf(h1 * sl, 0.f);
    float n2b = wave_sum(x0 * x0 + x1 * x1);
    float nb = fmaxf(sqrtf(n2b), MIN_NORM);
    float scb = tanh_c(nb) / nb;
    scb *= proj_factor(scb * scb * n2b);
    *reinterpret_cast<float2*>(&out[(size_t)v * 128 + l2]) =
        make_float2(x0 * scb, x1 * scb);
}

// ---------------- fallback (atomic path) ----------------
__global__ __launch_bounds__(256)
void agg_edges(const float* __restrict__ xtan, const int* __restrict__ src,
               const int* __restrict__ dst, const float* __restrict__ ew,
               float* __restrict__ agg, int n_edges) {
    int gt = blockIdx.x * blockDim.x + threadIdx.x;
    int e = gt >> 5;
    if (e >= n_edges) return;
    int c = (gt & 31) << 2;
    int sN = src[e], dN = dst[e];
    float w = ew[e];
    const float4 v = *reinterpret_cast<const float4*>(&xtan[(size_t)sN * 128 + c]);
    float* ap = &agg[(size_t)dN * 128 + c];
    atomicAdd(ap + 0, w * v.x);
    atomicAdd(ap + 1, w * v.y);
    atomicAdd(ap + 2, w * v.z);
    atomicAdd(ap + 3, w * v.w);
}

__global__ __launch_bounds__(256)
void hyp_act_kernel(const float* __restrict__ in, float* __restrict__ out, int n_rows) {
    int row = blockIdx.x * 4 + (threadIdx.x >> 6);
    if (row >= n_rows) return;
    int lane = threadIdx.x & 63;
    int l2 = lane << 1;
    const float2 v = *reinterpret_cast<const float2*>(&in[(size_t)row * 128 + l2]);
    float a0 = v.x, a1 = v.y;
    float n2 = wave_sum(a0 * a0 + a1 * a1);
    float n = fmaxf(sqrtf(n2), MIN_NORM);
    float sc = tanh_c(n) / n;
    float hn2 = sc * sc * n2;
    float f = proj_factor(hn2);
    sc *= f; hn2 *= f * f;
    float h0 = a0 * sc, h1 = a1 * sc;
    float hn = fmaxf(sqrtf(hn2), MIN_NORM);
    float sl = artanh_c(hn) / hn;
    float x0 = fmaxf(h0 * sl, 0.f), x1 = fmaxf(h1 * sl, 0.f);
    float n2b = wave_sum(x0 * x0 + x1 * x1);
    float nb = fmaxf(sqrtf(n2b), MIN_NORM);
    float scb = tanh_c(nb) / nb;
    scb *= proj_factor(scb * scb * n2b);
    *reinterpret_cast<float2*>(&out[(size_t)row * 128 + l2]) =
        make_float2(x0 * scb, x1 * scb);
}

extern "C" void kernel_launch(void* const* d_in, const int* in_sizes, int n_in,
                              void* d_out, int out_size, void* d_ws, size_t ws_size,
                              hipStream_t stream) {
    const float* x   = (const float*)d_in[0];
    const int*   src = (const int*)d_in[1];
    const int*   dst = (const int*)d_in[2];
    const float* ew  = (const float*)d_in[3];
    const float* W1  = (const float*)d_in[4];
    const float* b1  = (const float*)d_in[5];
    const float* W2  = (const float*)d_in[6];
    const float* b2  = (const float*)d_in[7];

    const int N = in_sizes[0] / 128;
    const int E = in_sizes[1];
    float* fout = (float*)d_out;

    const int tiles = (N + 15) >> 4;
    const int lin_blocks = (tiles + 3) / 4;

    const size_t need = (size_t)N * 128 * 4
                      + (size_t)E * 8
                      + ((size_t)(N + 1) + N + N + 512) * 4
                      + 256 * 4;

    if (ws_size >= need) {
        float* nbuf  = (float*)d_ws;
        uint2* epair = (uint2*)(nbuf + (size_t)N * 128);
        int* ptr     = (int*)(epair + E);
        int* cnt     = ptr + (N + 1);
        int* cursor  = cnt + N;
        int* bsum    = cursor + N;
        int* bscan   = bsum + 256;
        float* hb1   = (float*)(bscan + 256);
        float* hb2   = hb1 + 128;

        const int nbE = (E + 255) / 256;
        const int nbN = (N + 255) / 256;

        bias_kernel<<<1, 64, 0, stream>>>(b1, b2, hb1, hb2);

        hipMemsetAsync(cnt, 0, (size_t)N * 4, stream);
        hist_kernel<<<nbE, 256, 0, stream>>>(dst, cnt, E);
        scan1<<<nbN, 256, 0, stream>>>(cnt, ptr, bsum, N);
        scan2<<<1, 256, 0, stream>>>(bsum, bscan, nbN);
        scan3<<<nbN, 256, 0, stream>>>(bscan, ptr, cursor, N, E);
        scatter_kernel<<<nbE, 256, 0, stream>>>(src, dst, ew, cursor, epair, E);

        hyp_linear_tan_mfma<true><<<lin_blocks, 256, 0, stream>>>(x, W1, hb1, fout, N);
        gather_act<<<(N + 3) / 4, 256, 0, stream>>>(fout, ptr, epair, nbuf, N);
        hyp_linear_tan_mfma<false><<<lin_blocks, 256, 0, stream>>>(nbuf, W2, hb2, nbuf, N);
        gather_act<<<(N + 3) / 4, 256, 0, stream>>>(nbuf, ptr, epair, fout, N);
    } else {
        float* nbuf = (float*)d_ws;
        float* hb1  = nbuf + (size_t)N * 128;
        float* hb2  = hb1 + 128;
        const size_t node_bytes = (size_t)N * 128 * sizeof(float);
        const int agg_blocks = (int)(((size_t)E * 32 + 255) / 256);
        const int row_blocks = (N + 3) / 4;

        bias_kernel<<<1, 64, 0, stream>>>(b1, b2, hb1, hb2);
        hyp_linear_tan_mfma<true><<<lin_blocks, 256, 0, stream>>>(x, W1, hb1, fout, N);
        hipMemsetAsync(nbuf, 0, node_bytes, stream);
        agg_edges<<<agg_blocks, 256, 0, stream>>>(fout, src, dst, ew, nbuf, E);
        hyp_act_kernel<<<row_blocks, 256, 0, stream>>>(nbuf, nbuf, N);
        hyp_linear_tan_mfma<false><<<lin_blocks, 256, 0, stream>>>(nbuf, W2, hb2, nbuf, N);
        hipMemsetAsync(fout, 0, node_bytes, stream);
        agg_edges<<<agg_blocks, 256, 0, stream>>>(nbuf, src, dst, ew, fout, E);
        hyp_act_kernel<<<row_blocks, 256, 0, stream>>>(fout, fout, N);
    }
}

// Round 7
// 282.695 us; speedup vs baseline: 7.4072x; 1.0464x over previous
//
#include <hip/hip_runtime.h>
#include <math.h>

#define MIN_NORM 1e-15f
#define MAXNORM  0.996f          /* (1 - 4e-3)/sqrt(c), c=1 */
#define ARTANH_CLIP 0.99999988f  /* float(1.0 - 1e-7) */

typedef __bf16 bf16x8 __attribute__((ext_vector_type(8)));
typedef float  f32x4  __attribute__((ext_vector_type(4)));

union FragU { ushort u[8]; uint4 q; bf16x8 v; };

__device__ __forceinline__ float wave_sum(float v) {
#pragma unroll
    for (int off = 32; off > 0; off >>= 1) v += __shfl_xor(v, off, 64);
    return v;
}

__device__ __forceinline__ float artanh_c(float x) {
    x = fminf(fmaxf(x, -ARTANH_CLIP), ARTANH_CLIP);
    return 0.5f * (log1pf(x) - log1pf(-x));
}

__device__ __forceinline__ float tanh_c(float x) {
    return tanhf(fminf(fmaxf(x, -15.f), 15.f));
}

__device__ __forceinline__ float proj_factor(float n2) {
    float n = fmaxf(sqrtf(n2), MIN_NORM);
    return (n > MAXNORM) ? (MAXNORM / n) : 1.f;
}

__device__ __forceinline__ unsigned short f2bf(float f) {   // RNE
    unsigned u = __float_as_uint(f);
    return (unsigned short)((u + 0x7fffu + ((u >> 16) & 1u)) >> 16);
}
__device__ __forceinline__ float bf2f(unsigned short h) {
    return __uint_as_float((unsigned)h << 16);
}

__device__ __forceinline__ void red16_f4(float4& v) {
#pragma unroll
    for (int off = 1; off < 16; off <<= 1) {
        v.x += __shfl_xor(v.x, off, 64);
        v.y += __shfl_xor(v.y, off, 64);
        v.z += __shfl_xor(v.z, off, 64);
        v.w += __shfl_xor(v.w, off, 64);
    }
}

// component (r&3) of float4 held by group (r>>2): 4 bpermute + 3 selects
__device__ __forceinline__ float bcast_row(const float4& v, int r) {
    const int src = (r >> 2) << 4;
    const float a = __shfl(v.x, src, 64);
    const float b = __shfl(v.y, src, 64);
    const float c = __shfl(v.z, src, 64);
    const float d = __shfl(v.w, src, 64);
    const float lo = (r & 1) ? b : a;
    const float hi = (r & 1) ? d : c;
    return (r & 2) ? hi : lo;
}

// hyp_bias = proj(expmap0(b, c), c) for both layers. 1 block x 64 threads.
__global__ void bias_kernel(const float* __restrict__ b1, const float* __restrict__ b2,
                            float* __restrict__ hb1, float* __restrict__ hb2) {
    int lane = threadIdx.x;
#pragma unroll
    for (int j = 0; j < 2; ++j) {
        const float* b = j ? b2 : b1;
        float* hb = j ? hb2 : hb1;
        float v0 = b[lane], v1 = b[lane + 64];
        float n2 = wave_sum(v0 * v0 + v1 * v1);
        float n = fmaxf(sqrtf(n2), MIN_NORM);
        float sc = tanh_c(n) / n;
        sc *= proj_factor(sc * sc * n2);
        hb[lane] = v0 * sc;
        hb[lane + 64] = v1 * sc;
    }
}

// Precompute W -> swizzled bf16 hi/lo pack (64KB per layer: [0,32K)=hi, [32K,64K)=lo).
// Layout matches the LDS image the linear kernel expects (byte ^= (row&7)<<4).
__global__ void prep_w(const float* __restrict__ W1, const float* __restrict__ W2,
                       char* __restrict__ g1, char* __restrict__ g2) {
    const int b = blockIdx.x;
    const float* W = (b < 16) ? W1 : W2;
    char* out = (b < 16) ? g1 : g2;
    const int i = (((b & 15) * 256) + threadIdx.x) * 4;   // element index
    const int row = i >> 7, col = i & 127;
    const float4 w4 = *reinterpret_cast<const float4*>(&W[i]);
    ushort4 h, l;
    h.x = f2bf(w4.x); l.x = f2bf(w4.x - bf2f(h.x));
    h.y = f2bf(w4.y); l.y = f2bf(w4.y - bf2f(h.y));
    h.z = f2bf(w4.z); l.z = f2bf(w4.z - bf2f(h.z));
    h.w = f2bf(w4.w); l.w = f2bf(w4.w - bf2f(h.w));
    const unsigned byte = (unsigned)((row << 8) + (col << 1)) ^ (unsigned)((row & 7) << 4);
    *reinterpret_cast<ushort4*>(out + byte) = h;
    *reinterpret_cast<ushort4*>(out + 32768 + byte) = l;
}

// ---------------- CSR build ----------------

__global__ void hist_kernel(const int* __restrict__ dst, int* __restrict__ cnt, int E) {
    int e = blockIdx.x * blockDim.x + threadIdx.x;
    if (e < E) atomicAdd(&cnt[dst[e]], 1);
}

__global__ void scan1(const int* __restrict__ cnt, int* __restrict__ ptr,
                      int* __restrict__ bsum, int N) {
    __shared__ int s[256];
    const int t = threadIdx.x;
    const int i = blockIdx.x * 256 + t;
    int v = (i < N) ? cnt[i] : 0;
    s[t] = v;
    __syncthreads();
#pragma unroll
    for (int off = 1; off < 256; off <<= 1) {
        int add = (t >= off) ? s[t - off] : 0;
        __syncthreads();
        s[t] += add;
        __syncthreads();
    }
    if (i < N) ptr[i] = s[t] - v;
    if (t == 255) bsum[blockIdx.x] = s[255];
}

__global__ void scan2(const int* __restrict__ bsum, int* __restrict__ bscan, int nb) {
    __shared__ int s[256];
    const int t = threadIdx.x;
    int v = (t < nb) ? bsum[t] : 0;
    s[t] = v;
    __syncthreads();
#pragma unroll
    for (int off = 1; off < 256; off <<= 1) {
        int add = (t >= off) ? s[t - off] : 0;
        __syncthreads();
        s[t] += add;
        __syncthreads();
    }
    bscan[t] = s[t] - v;
}

__global__ void scan3(const int* __restrict__ bscan, int* __restrict__ ptr,
                      int* __restrict__ cursor, int N, int E) {
    const int i = blockIdx.x * blockDim.x + threadIdx.x;
    if (i < N) {
        const int p = ptr[i] + bscan[i >> 8];
        ptr[i] = p;
        cursor[i] = p;
    }
    if (i == 0) ptr[N] = E;
}

__global__ void scatter_kernel(const int* __restrict__ src, const int* __restrict__ dst,
                               const float* __restrict__ ew, int* __restrict__ cursor,
                               uint2* __restrict__ epair, int E) {
    int e = blockIdx.x * blockDim.x + threadIdx.x;
    if (e >= E) return;
    int pos = atomicAdd(&cursor[dst[e]], 1);
    epair[pos] = make_uint2((unsigned)src[e], __float_as_uint(ew[e]));
}

// ---------------- MFMA fused linear ----------------
// raw = x @ W^T via bf16x3 split. Epilogue collapsed to out = P*raw + Q*yb with
// per-row scalars P,Q computed ONCE per lane (lane handles row lane&15), so the
// transcendental chain runs 1x/lane instead of 4x. W staged by plain 64KB copy
// of the precomputed swizzled pack (no conversions in hot kernel).
template <bool PRELUDE>
__global__ __launch_bounds__(256, 2)
void hyp_linear_tan_mfma(const float* __restrict__ xin, const char* __restrict__ gWpack,
                         const float* __restrict__ hb, float* __restrict__ xtan,
                         int n_rows) {
    __shared__ __align__(16) char sW[65536];   // [0,32K)=hi swz, [32K,64K)=lo swz

    const int tid = threadIdx.x;
    {
        const uint4* gsrc = reinterpret_cast<const uint4*>(gWpack);
        uint4* ldst = reinterpret_cast<uint4*>(sW);
#pragma unroll
        for (int i = 0; i < 16; ++i) ldst[tid + i * 256] = gsrc[tid + i * 256];
    }

    const int lane = tid & 63, wid = tid >> 6;
    const int r15 = lane & 15, g = lane >> 4;

    // bias fragment: yb[ct] = hb[16*ct + r15]; y2 = sum over 128 cols
    float yb[8];
    float y2p = 0.f;
#pragma unroll
    for (int t = 0; t < 8; ++t) { yb[t] = hb[t * 16 + r15]; y2p += yb[t] * yb[t]; }
#pragma unroll
    for (int off = 1; off < 16; off <<= 1) y2p += __shfl_xor(y2p, off, 64);
    const float y2 = y2p;

    __syncthreads();

    const int tiles = (n_rows + 15) >> 4;
    const unsigned lswz = (unsigned)((r15 & 7) << 4);

    for (int tile = blockIdx.x * 4 + wid; tile < tiles; tile += gridDim.x * 4) {
        const int rowbase = tile << 4;
        const int myrow = rowbase + r15;
        const bool rok = (myrow < n_rows);
        const float* xr = xin + (size_t)myrow * 128 + g * 8;

        // load 32 x-values (f32), hi/lo bf16 A-frags via native casts, norm partial
        bf16x8 ah[4], al[4];
        float ss = 0.f;
#pragma unroll
        for (int kc = 0; kc < 4; ++kc) {
            float4 xa = make_float4(0.f, 0.f, 0.f, 0.f), xb = xa;
            if (rok) {
                xa = *reinterpret_cast<const float4*>(xr + kc * 32);
                xb = *reinterpret_cast<const float4*>(xr + kc * 32 + 4);
            }
            ss += xa.x * xa.x + xa.y * xa.y + xa.z * xa.z + xa.w * xa.w
                + xb.x * xb.x + xb.y * xb.y + xb.z * xb.z + xb.w * xb.w;
            ah[kc][0] = (__bf16)xa.x; al[kc][0] = (__bf16)(xa.x - (float)ah[kc][0]);
            ah[kc][1] = (__bf16)xa.y; al[kc][1] = (__bf16)(xa.y - (float)ah[kc][1]);
            ah[kc][2] = (__bf16)xa.z; al[kc][2] = (__bf16)(xa.z - (float)ah[kc][2]);
            ah[kc][3] = (__bf16)xa.w; al[kc][3] = (__bf16)(xa.w - (float)ah[kc][3]);
            ah[kc][4] = (__bf16)xb.x; al[kc][4] = (__bf16)(xb.x - (float)ah[kc][4]);
            ah[kc][5] = (__bf16)xb.y; al[kc][5] = (__bf16)(xb.y - (float)ah[kc][5]);
            ah[kc][6] = (__bf16)xb.z; al[kc][6] = (__bf16)(xb.z - (float)ah[kc][6]);
            ah[kc][7] = (__bf16)xb.w; al[kc][7] = (__bf16)(xb.w - (float)ah[kc][7]);
        }
        ss += __shfl_xor(ss, 16, 64);
        ss += __shfl_xor(ss, 32, 64);   // n2 of row rowbase + (lane&15)

        f32x4 acc[8];
#pragma unroll
        for (int ct = 0; ct < 8; ++ct) acc[ct] = (f32x4){0.f, 0.f, 0.f, 0.f};

#pragma unroll
        for (int kc = 0; kc < 4; ++kc) {
#pragma unroll
            for (int ct = 0; ct < 8; ++ct) {
                const unsigned byte =
                    ((unsigned)((ct << 12) + (r15 << 8) + (kc << 6) + (g << 4))) ^ lswz;
                FragU bh, bl;
                bh.q = *reinterpret_cast<const uint4*>(sW + byte);
                bl.q = *reinterpret_cast<const uint4*>(sW + 32768 + byte);
                acc[ct] = __builtin_amdgcn_mfma_f32_16x16x32_bf16(ah[kc], bh.v, acc[ct], 0, 0, 0);
                acc[ct] = __builtin_amdgcn_mfma_f32_16x16x32_bf16(ah[kc], bl.v, acc[ct], 0, 0, 0);
                acc[ct] = __builtin_amdgcn_mfma_f32_16x16x32_bf16(al[kc], bh.v, acc[ct], 0, 0, 0);
            }
        }

        // ---- packed reductions: rawn2 and xyraw per reg-row ----
        float4 r2 = make_float4(0.f, 0.f, 0.f, 0.f);
        float4 xyv = make_float4(0.f, 0.f, 0.f, 0.f);
#pragma unroll
        for (int ct = 0; ct < 8; ++ct) {
            r2.x += acc[ct][0] * acc[ct][0];
            r2.y += acc[ct][1] * acc[ct][1];
            r2.z += acc[ct][2] * acc[ct][2];
            r2.w += acc[ct][3] * acc[ct][3];
            xyv.x += acc[ct][0] * yb[ct];
            xyv.y += acc[ct][1] * yb[ct];
            xyv.z += acc[ct][2] * yb[ct];
            xyv.w += acc[ct][3] * yb[ct];
        }
        red16_f4(r2);
        red16_f4(xyv);

        // ---- per-row scalar chain, ONE row per lane (row = lane&15) ----
        const float rn2 = bcast_row(r2, r15);
        const float xyr = bcast_row(xyv, r15);
        const float n2v = ss;

        const float n = fmaxf(sqrtf(n2v), MIN_NORM);
        float sc = 1.f;
        if (PRELUDE) {                  // encode proj(expmap0(x)) as row scalar
            sc = tanh_c(n) / n;
            sc *= proj_factor(sc * sc * n2v);
        }
        const float xn = fmaxf(sc * n, MIN_NORM);
        const float mxn = fmaxf(sc * sqrtf(rn2), MIN_NORM);
        const float s = tanh_c(mxn / xn * artanh_c(xn));
        const float sl0 = (s * sc) / mxn;           // scale on raw (mobius_matvec)
        float m2 = rn2 * sl0 * sl0;
        const float f = proj_factor(m2);            // proj
        const float scl = sl0 * f;
        m2 *= f * f;
        const float xy = scl * xyr;                 // <m, yb>
        const float cx = 1.f + 2.f * xy + y2;
        const float cy = 1.f - m2;
        const float rdn = 1.f / fmaxf(1.f + 2.f * xy + m2 * y2, MIN_NORM);
        const float A = cx * scl * rdn;             // o = A*raw + B*yb
        const float B = cy * rdn;
        const float on2 = A * A * rn2 + 2.f * A * B * xyr + B * B * y2;
        const float f2 = proj_factor(on2);          // proj
        const float onn = fmaxf(sqrtf(on2) * f2, MIN_NORM);
        const float slg = artanh_c(onn) / onn;      // logmap0
        const float P = slg * f2 * A;
        const float Q = slg * f2 * B;

        // ---- broadcast P,Q per reg-row; apply + store ----
#pragma unroll
        for (int reg = 0; reg < 4; ++reg) {
            const float Pr = __shfl(P, 4 * g + reg, 64);
            const float Qr = __shfl(Q, 4 * g + reg, 64);
            const int row = rowbase + 4 * g + reg;
            if (row < n_rows) {
                float* orow = xtan + (size_t)row * 128 + r15;
#pragma unroll
                for (int ct = 0; ct < 8; ++ct)
                    orow[ct * 16] = fmaf(Pr, acc[ct][reg], Qr * yb[ct]);
            }
        }
    }
}

// ---------------- gather aggregate + fused hyp_act ----------------
__global__ __launch_bounds__(256)
void gather_act(const float* __restrict__ xtan, const int* __restrict__ ptr,
                const uint2* __restrict__ epair, float* __restrict__ out, int n_rows) {
    const int v = blockIdx.x * 4 + (threadIdx.x >> 6);
    if (v >= n_rows) return;
    const int lane = threadIdx.x & 63, l2 = lane << 1;
    const int beg = ptr[v], end = ptr[v + 1];
    float a0 = 0.f, a1 = 0.f;
    int i = beg;
    for (; i + 1 < end; i += 2) {
        const uint2 p0 = epair[i], p1 = epair[i + 1];
        const float2 x0 = *reinterpret_cast<const float2*>(&xtan[(size_t)p0.x * 128 + l2]);
        const float2 x1 = *reinterpret_cast<const float2*>(&xtan[(size_t)p1.x * 128 + l2]);
        const float w0 = __uint_as_float(p0.y), w1 = __uint_as_float(p1.y);
        a0 = fmaf(w0, x0.x, a0); a1 = fmaf(w0, x0.y, a1);
        a0 = fmaf(w1, x1.x, a0); a1 = fmaf(w1, x1.y, a1);
    }
    if (i < end) {
        const uint2 p = epair[i];
        const float2 xv = *reinterpret_cast<const float2*>(&xtan[(size_t)p.x * 128 + l2]);
        const float w = __uint_as_float(p.y);
        a0 = fmaf(w, xv.x, a0); a1 = fmaf(w, xv.y, a1);
    }

    float n2 = wave_sum(a0 * a0 + a1 * a1);
    float n = fmaxf(sqrtf(n2), MIN_NORM);
    float sc = tanh_c(n) / n;
    float hn2 = sc * sc * n2;
    float f = proj_factor(hn2);
    sc *= f; hn2 *= f * f;
    float h0 = a0 * sc, h1 = a1 * sc;
    float hn = fmaxf(sqrtf(hn2), MIN_NORM);
    float sl = artanh_c(hn) / hn;
    float x0 = fmaxf(h0 * sl, 0.f), x1 = fmaxf(h1 * sl, 0.f);
    float n2b = wave_sum(x0 * x0 + x1 * x1);
    float nb = fmaxf(sqrtf(n2b), MIN_NORM);
    float scb = tanh_c(nb) / nb;
    scb *= proj_factor(scb * scb * n2b);
    *reinterpret_cast<float2*>(&out[(size_t)v * 128 + l2]) =
        make_float2(x0 * scb, x1 * scb);
}

// ---------------- fallback (atomic path) ----------------
__global__ __launch_bounds__(256)
void agg_edges(const float* __restrict__ xtan, const int* __restrict__ src,
               const int* __restrict__ dst, const float* __restrict__ ew,
               float* __restrict__ agg, int n_edges) {
    int gt = blockIdx.x * blockDim.x + threadIdx.x;
    int e = gt >> 5;
    if (e >= n_edges) return;
    int c = (gt & 31) << 2;
    int sN = src[e], dN = dst[e];
    float w = ew[e];
    const float4 v = *reinterpret_cast<const float4*>(&xtan[(size_t)sN * 128 + c]);
    float* ap = &agg[(size_t)dN * 128 + c];
    atomicAdd(ap + 0, w * v.x);
    atomicAdd(ap + 1, w * v.y);
    atomicAdd(ap + 2, w * v.z);
    atomicAdd(ap + 3, w * v.w);
}

__global__ __launch_bounds__(256)
void hyp_act_kernel(const float* __restrict__ in, float* __restrict__ out, int n_rows) {
    int row = blockIdx.x * 4 + (threadIdx.x >> 6);
    if (row >= n_rows) return;
    int lane = threadIdx.x & 63;
    int l2 = lane << 1;
    const float2 v = *reinterpret_cast<const float2*>(&in[(size_t)row * 128 + l2]);
    float a0 = v.x, a1 = v.y;
    float n2 = wave_sum(a0 * a0 + a1 * a1);
    float n = fmaxf(sqrtf(n2), MIN_NORM);
    float sc = tanh_c(n) / n;
    float hn2 = sc * sc * n2;
    float f = proj_factor(hn2);
    sc *= f; hn2 *= f * f;
    float h0 = a0 * sc, h1 = a1 * sc;
    float hn = fmaxf(sqrtf(hn2), MIN_NORM);
    float sl = artanh_c(hn) / hn;
    float x0 = fmaxf(h0 * sl, 0.f), x1 = fmaxf(h1 * sl, 0.f);
    float n2b = wave_sum(x0 * x0 + x1 * x1);
    float nb = fmaxf(sqrtf(n2b), MIN_NORM);
    float scb = tanh_c(nb) / nb;
    scb *= proj_factor(scb * scb * n2b);
    *reinterpret_cast<float2*>(&out[(size_t)row * 128 + l2]) =
        make_float2(x0 * scb, x1 * scb);
}

extern "C" void kernel_launch(void* const* d_in, const int* in_sizes, int n_in,
                              void* d_out, int out_size, void* d_ws, size_t ws_size,
                              hipStream_t stream) {
    const float* x   = (const float*)d_in[0];
    const int*   src = (const int*)d_in[1];
    const int*   dst = (const int*)d_in[2];
    const float* ew  = (const float*)d_in[3];
    const float* W1  = (const float*)d_in[4];
    const float* b1  = (const float*)d_in[5];
    const float* W2  = (const float*)d_in[6];
    const float* b2  = (const float*)d_in[7];

    const int N = in_sizes[0] / 128;
    const int E = in_sizes[1];
    float* fout = (float*)d_out;

    const int tiles = (N + 15) >> 4;
    const int lin_blocks = (tiles + 3) / 4;

    const size_t need = 131072                      // gW packs (2 x 64KB)
                      + (size_t)N * 128 * 4         // nbuf
                      + (size_t)E * 8               // epair
                      + ((size_t)(N + 1) + N + N + 512) * 4
                      + 256 * 4;                    // hb1/hb2

    if (ws_size >= need) {
        char*  base  = (char*)d_ws;
        char*  gW1p  = base;                        // 64KB
        char*  gW2p  = base + 65536;                // 64KB
        float* nbuf  = (float*)(base + 131072);
        uint2* epair = (uint2*)(nbuf + (size_t)N * 128);
        int* ptr     = (int*)(epair + E);
        int* cnt     = ptr + (N + 1);
        int* cursor  = cnt + N;
        int* bsum    = cursor + N;
        int* bscan   = bsum + 256;
        float* hb1   = (float*)(bscan + 256);
        float* hb2   = hb1 + 128;

        const int nbE = (E + 255) / 256;
        const int nbN = (N + 255) / 256;

        prep_w<<<32, 256, 0, stream>>>(W1, W2, gW1p, gW2p);
        bias_kernel<<<1, 64, 0, stream>>>(b1, b2, hb1, hb2);

        hipMemsetAsync(cnt, 0, (size_t)N * 4, stream);
        hist_kernel<<<nbE, 256, 0, stream>>>(dst, cnt, E);
        scan1<<<nbN, 256, 0, stream>>>(cnt, ptr, bsum, N);
        scan2<<<1, 256, 0, stream>>>(bsum, bscan, nbN);
        scan3<<<nbN, 256, 0, stream>>>(bscan, ptr, cursor, N, E);
        scatter_kernel<<<nbE, 256, 0, stream>>>(src, dst, ew, cursor, epair, E);

        hyp_linear_tan_mfma<true><<<lin_blocks, 256, 0, stream>>>(x, gW1p, hb1, fout, N);
        gather_act<<<(N + 3) / 4, 256, 0, stream>>>(fout, ptr, epair, nbuf, N);
        hyp_linear_tan_mfma<false><<<lin_blocks, 256, 0, stream>>>(nbuf, gW2p, hb2, nbuf, N);
        gather_act<<<(N + 3) / 4, 256, 0, stream>>>(nbuf, ptr, epair, fout, N);
    } else {
        char*  gW1p = (char*)d_ws;
        char*  gW2p = gW1p + 65536;
        float* nbuf = (float*)(gW2p + 65536);
        float* hb1  = nbuf + (size_t)N * 128;
        float* hb2  = hb1 + 128;
        const size_t node_bytes = (size_t)N * 128 * sizeof(float);
        const int agg_blocks = (int)(((size_t)E * 32 + 255) / 256);
        const int row_blocks = (N + 3) / 4;

        prep_w<<<32, 256, 0, stream>>>(W1, W2, gW1p, gW2p);
        bias_kernel<<<1, 64, 0, stream>>>(b1, b2, hb1, hb2);
        hyp_linear_tan_mfma<true><<<lin_blocks, 256, 0, stream>>>(x, gW1p, hb1, fout, N);
        hipMemsetAsync(nbuf, 0, node_bytes, stream);
        agg_edges<<<agg_blocks, 256, 0, stream>>>(fout, src, dst, ew, nbuf, E);
        hyp_act_kernel<<<row_blocks, 256, 0, stream>>>(nbuf, nbuf, N);
        hyp_linear_tan_mfma<false><<<lin_blocks, 256, 0, stream>>>(nbuf, gW2p, hb2, nbuf, N);
        hipMemsetAsync(fout, 0, node_bytes, stream);
        agg_edges<<<agg_blocks, 256, 0, stream>>>(nbuf, src, dst, ew, fout, E);
        hyp_act_kernel<<<row_blocks, 256, 0, stream>>>(fout, fout, N);
    }
}

// Round 8
// 273.481 us; speedup vs baseline: 7.6567x; 1.0337x over previous
//
#include <hip/hip_runtime.h>
#include <math.h>

#define MIN_NORM 1e-15f
#define MAXNORM  0.996f          /* (1 - 4e-3)/sqrt(c), c=1 */
#define ARTANH_CLIP 0.99999988f  /* float(1.0 - 1e-7) */

typedef __bf16 bf16x8 __attribute__((ext_vector_type(8)));
typedef float  f32x4  __attribute__((ext_vector_type(4)));

union FragU { ushort u[8]; uint4 q; bf16x8 v; };

__device__ __forceinline__ float wave_sum(float v) {
#pragma unroll
    for (int off = 32; off > 0; off >>= 1) v += __shfl_xor(v, off, 64);
    return v;
}

__device__ __forceinline__ float artanh_c(float x) {
    x = fminf(fmaxf(x, -ARTANH_CLIP), ARTANH_CLIP);
    return 0.5f * (log1pf(x) - log1pf(-x));
}

__device__ __forceinline__ float tanh_c(float x) {
    return tanhf(fminf(fmaxf(x, -15.f), 15.f));
}

__device__ __forceinline__ float proj_factor(float n2) {
    float n = fmaxf(sqrtf(n2), MIN_NORM);
    return (n > MAXNORM) ? (MAXNORM / n) : 1.f;
}

__device__ __forceinline__ unsigned short f2bf(float f) {   // RNE
    unsigned u = __float_as_uint(f);
    return (unsigned short)((u + 0x7fffu + ((u >> 16) & 1u)) >> 16);
}
__device__ __forceinline__ float bf2f(unsigned short h) {
    return __uint_as_float((unsigned)h << 16);
}

__device__ __forceinline__ void red16_f4(float4& v) {
#pragma unroll
    for (int off = 1; off < 16; off <<= 1) {
        v.x += __shfl_xor(v.x, off, 64);
        v.y += __shfl_xor(v.y, off, 64);
        v.z += __shfl_xor(v.z, off, 64);
        v.w += __shfl_xor(v.w, off, 64);
    }
}

// component (r&3) of float4 held by group (r>>2): 4 shfl + 3 selects
__device__ __forceinline__ float bcast_row(const float4& v, int r) {
    const int src = (r >> 2) << 4;
    const float a = __shfl(v.x, src, 64);
    const float b = __shfl(v.y, src, 64);
    const float c = __shfl(v.z, src, 64);
    const float d = __shfl(v.w, src, 64);
    const float lo = (r & 1) ? b : a;
    const float hi = (r & 1) ? d : c;
    return (r & 2) ? hi : lo;
}

// -------- fused setup: prep_w (blocks 0..31) + bias (block 32) + hist (33..) --------
__global__ __launch_bounds__(256)
void setup_kernel(const float* __restrict__ W1, const float* __restrict__ W2,
                  char* __restrict__ g1, char* __restrict__ g2,
                  const float* __restrict__ b1, const float* __restrict__ b2,
                  float* __restrict__ hb1, float* __restrict__ hb2,
                  const int* __restrict__ dst, int* __restrict__ cnt, int E) {
    const int b = blockIdx.x;
    if (b < 32) {
        // W -> swizzled bf16 hi/lo pack (64KB/layer: [0,32K)=hi, [32K,64K)=lo)
        const float* W = (b < 16) ? W1 : W2;
        char* out = (b < 16) ? g1 : g2;
        const int i = (((b & 15) * 256) + threadIdx.x) * 4;   // element index
        const int row = i >> 7, col = i & 127;
        const float4 w4 = *reinterpret_cast<const float4*>(&W[i]);
        ushort4 h, l;
        h.x = f2bf(w4.x); l.x = f2bf(w4.x - bf2f(h.x));
        h.y = f2bf(w4.y); l.y = f2bf(w4.y - bf2f(h.y));
        h.z = f2bf(w4.z); l.z = f2bf(w4.z - bf2f(h.z));
        h.w = f2bf(w4.w); l.w = f2bf(w4.w - bf2f(h.w));
        const unsigned byte = (unsigned)((row << 8) + (col << 1)) ^ (unsigned)((row & 7) << 4);
        *reinterpret_cast<ushort4*>(out + byte) = h;
        *reinterpret_cast<ushort4*>(out + 32768 + byte) = l;
    } else if (b == 32) {
        if (threadIdx.x < 64) {   // one full wave: hyp_bias for both layers
            const int lane = threadIdx.x;
#pragma unroll
            for (int j = 0; j < 2; ++j) {
                const float* bb = j ? b2 : b1;
                float* hb = j ? hb2 : hb1;
                float v0 = bb[lane], v1 = bb[lane + 64];
                float n2 = wave_sum(v0 * v0 + v1 * v1);
                float n = fmaxf(sqrtf(n2), MIN_NORM);
                float sc = tanh_c(n) / n;
                sc *= proj_factor(sc * sc * n2);
                hb[lane] = v0 * sc;
                hb[lane + 64] = v1 * sc;
            }
        }
    } else {
        const int e = (b - 33) * 256 + threadIdx.x;
        if (e < E) atomicAdd(&cnt[dst[e]], 1);
    }
}

// ---------------- CSR build (scan + scatter) ----------------

__global__ void scan1(const int* __restrict__ cnt, int* __restrict__ ptr,
                      int* __restrict__ bsum, int N) {
    __shared__ int s[256];
    const int t = threadIdx.x;
    const int i = blockIdx.x * 256 + t;
    int v = (i < N) ? cnt[i] : 0;
    s[t] = v;
    __syncthreads();
#pragma unroll
    for (int off = 1; off < 256; off <<= 1) {
        int add = (t >= off) ? s[t - off] : 0;
        __syncthreads();
        s[t] += add;
        __syncthreads();
    }
    if (i < N) ptr[i] = s[t] - v;
    if (t == 255) bsum[blockIdx.x] = s[255];
}

__global__ void scan2(const int* __restrict__ bsum, int* __restrict__ bscan, int nb) {
    __shared__ int s[256];
    const int t = threadIdx.x;
    int v = (t < nb) ? bsum[t] : 0;
    s[t] = v;
    __syncthreads();
#pragma unroll
    for (int off = 1; off < 256; off <<= 1) {
        int add = (t >= off) ? s[t - off] : 0;
        __syncthreads();
        s[t] += add;
        __syncthreads();
    }
    bscan[t] = s[t] - v;
}

__global__ void scan3(const int* __restrict__ bscan, int* __restrict__ ptr,
                      int* __restrict__ cursor, int N, int E) {
    const int i = blockIdx.x * blockDim.x + threadIdx.x;
    if (i < N) {
        const int p = ptr[i] + bscan[i >> 8];
        ptr[i] = p;
        cursor[i] = p;
    }
    if (i == 0) ptr[N] = E;
}

// epair.x = src * 256 (byte offset of bf16 row), epair.y = bits(weight)
__global__ void scatter_kernel(const int* __restrict__ src, const int* __restrict__ dst,
                               const float* __restrict__ ew, int* __restrict__ cursor,
                               uint2* __restrict__ epair, int E) {
    int e = blockIdx.x * blockDim.x + threadIdx.x;
    if (e >= E) return;
    int pos = atomicAdd(&cursor[dst[e]], 1);
    epair[pos] = make_uint2((unsigned)src[e] << 8, __float_as_uint(ew[e]));
}

// ---------------- MFMA fused linear ----------------
// raw = x @ W^T via bf16x3 split. Epilogue collapsed to out = P*raw + Q*yb with
// per-row scalars P,Q computed once per lane. Output optionally bf16 (x_tan for
// the gather) or f32 (fallback path).
template <bool PRELUDE, bool BF16OUT>
__global__ __launch_bounds__(256, 2)
void hyp_linear_tan_mfma(const float* __restrict__ xin, const char* __restrict__ gWpack,
                         const float* __restrict__ hb, void* __restrict__ xtan,
                         int n_rows) {
    __shared__ __align__(16) char sW[65536];   // [0,32K)=hi swz, [32K,64K)=lo swz

    const int tid = threadIdx.x;
    {
        const uint4* gsrc = reinterpret_cast<const uint4*>(gWpack);
        uint4* ldst = reinterpret_cast<uint4*>(sW);
#pragma unroll
        for (int i = 0; i < 16; ++i) ldst[tid + i * 256] = gsrc[tid + i * 256];
    }

    const int lane = tid & 63, wid = tid >> 6;
    const int r15 = lane & 15, g = lane >> 4;

    // bias fragment: yb[ct] = hb[16*ct + r15]; y2 = sum over 128 cols
    float yb[8];
    float y2p = 0.f;
#pragma unroll
    for (int t = 0; t < 8; ++t) { yb[t] = hb[t * 16 + r15]; y2p += yb[t] * yb[t]; }
#pragma unroll
    for (int off = 1; off < 16; off <<= 1) y2p += __shfl_xor(y2p, off, 64);
    const float y2 = y2p;

    __syncthreads();

    const int tiles = (n_rows + 15) >> 4;
    const unsigned lswz = (unsigned)((r15 & 7) << 4);

    for (int tile = blockIdx.x * 4 + wid; tile < tiles; tile += gridDim.x * 4) {
        const int rowbase = tile << 4;
        const int myrow = rowbase + r15;
        const bool rok = (myrow < n_rows);
        const float* xr = xin + (size_t)myrow * 128 + g * 8;

        bf16x8 ah[4], al[4];
        float ss = 0.f;
#pragma unroll
        for (int kc = 0; kc < 4; ++kc) {
            float4 xa = make_float4(0.f, 0.f, 0.f, 0.f), xb = xa;
            if (rok) {
                xa = *reinterpret_cast<const float4*>(xr + kc * 32);
                xb = *reinterpret_cast<const float4*>(xr + kc * 32 + 4);
            }
            ss += xa.x * xa.x + xa.y * xa.y + xa.z * xa.z + xa.w * xa.w
                + xb.x * xb.x + xb.y * xb.y + xb.z * xb.z + xb.w * xb.w;
            ah[kc][0] = (__bf16)xa.x; al[kc][0] = (__bf16)(xa.x - (float)ah[kc][0]);
            ah[kc][1] = (__bf16)xa.y; al[kc][1] = (__bf16)(xa.y - (float)ah[kc][1]);
            ah[kc][2] = (__bf16)xa.z; al[kc][2] = (__bf16)(xa.z - (float)ah[kc][2]);
            ah[kc][3] = (__bf16)xa.w; al[kc][3] = (__bf16)(xa.w - (float)ah[kc][3]);
            ah[kc][4] = (__bf16)xb.x; al[kc][4] = (__bf16)(xb.x - (float)ah[kc][4]);
            ah[kc][5] = (__bf16)xb.y; al[kc][5] = (__bf16)(xb.y - (float)ah[kc][5]);
            ah[kc][6] = (__bf16)xb.z; al[kc][6] = (__bf16)(xb.z - (float)ah[kc][6]);
            ah[kc][7] = (__bf16)xb.w; al[kc][7] = (__bf16)(xb.w - (float)ah[kc][7]);
        }
        ss += __shfl_xor(ss, 16, 64);
        ss += __shfl_xor(ss, 32, 64);   // n2 of row rowbase + (lane&15)

        f32x4 acc[8];
#pragma unroll
        for (int ct = 0; ct < 8; ++ct) acc[ct] = (f32x4){0.f, 0.f, 0.f, 0.f};

#pragma unroll
        for (int kc = 0; kc < 4; ++kc) {
#pragma unroll
            for (int ct = 0; ct < 8; ++ct) {
                const unsigned byte =
                    ((unsigned)((ct << 12) + (r15 << 8) + (kc << 6) + (g << 4))) ^ lswz;
                FragU bh, bl;
                bh.q = *reinterpret_cast<const uint4*>(sW + byte);
                bl.q = *reinterpret_cast<const uint4*>(sW + 32768 + byte);
                acc[ct] = __builtin_amdgcn_mfma_f32_16x16x32_bf16(ah[kc], bh.v, acc[ct], 0, 0, 0);
                acc[ct] = __builtin_amdgcn_mfma_f32_16x16x32_bf16(ah[kc], bl.v, acc[ct], 0, 0, 0);
                acc[ct] = __builtin_amdgcn_mfma_f32_16x16x32_bf16(al[kc], bh.v, acc[ct], 0, 0, 0);
            }
        }

        // ---- packed reductions: rawn2 and xyraw per reg-row ----
        float4 r2 = make_float4(0.f, 0.f, 0.f, 0.f);
        float4 xyv = make_float4(0.f, 0.f, 0.f, 0.f);
#pragma unroll
        for (int ct = 0; ct < 8; ++ct) {
            r2.x += acc[ct][0] * acc[ct][0];
            r2.y += acc[ct][1] * acc[ct][1];
            r2.z += acc[ct][2] * acc[ct][2];
            r2.w += acc[ct][3] * acc[ct][3];
            xyv.x += acc[ct][0] * yb[ct];
            xyv.y += acc[ct][1] * yb[ct];
            xyv.z += acc[ct][2] * yb[ct];
            xyv.w += acc[ct][3] * yb[ct];
        }
        red16_f4(r2);
        red16_f4(xyv);

        // ---- per-row scalar chain, ONE row per lane (row = lane&15) ----
        const float rn2 = bcast_row(r2, r15);
        const float xyr = bcast_row(xyv, r15);
        const float n2v = ss;

        const float n = fmaxf(sqrtf(n2v), MIN_NORM);
        float sc = 1.f;
        if (PRELUDE) {
            sc = tanh_c(n) / n;
            sc *= proj_factor(sc * sc * n2v);
        }
        const float xn = fmaxf(sc * n, MIN_NORM);
        const float mxn = fmaxf(sc * sqrtf(rn2), MIN_NORM);
        const float s = tanh_c(mxn / xn * artanh_c(xn));
        const float sl0 = (s * sc) / mxn;
        float m2 = rn2 * sl0 * sl0;
        const float f = proj_factor(m2);
        const float scl = sl0 * f;
        m2 *= f * f;
        const float xy = scl * xyr;
        const float cx = 1.f + 2.f * xy + y2;
        const float cy = 1.f - m2;
        const float rdn = 1.f / fmaxf(1.f + 2.f * xy + m2 * y2, MIN_NORM);
        const float A = cx * scl * rdn;             // o = A*raw + B*yb
        const float B = cy * rdn;
        const float on2 = A * A * rn2 + 2.f * A * B * xyr + B * B * y2;
        const float f2 = proj_factor(on2);
        const float onn = fmaxf(sqrtf(on2) * f2, MIN_NORM);
        const float slg = artanh_c(onn) / onn;
        const float P = slg * f2 * A;
        const float Q = slg * f2 * B;

#pragma unroll
        for (int reg = 0; reg < 4; ++reg) {
            const float Pr = __shfl(P, 4 * g + reg, 64);
            const float Qr = __shfl(Q, 4 * g + reg, 64);
            const int row = rowbase + 4 * g + reg;
            if (row < n_rows) {
                if (BF16OUT) {
                    ushort* orow = (ushort*)xtan + (size_t)row * 128 + r15;
#pragma unroll
                    for (int ct = 0; ct < 8; ++ct) {
                        const float v = fmaf(Pr, acc[ct][reg], Qr * yb[ct]);
                        orow[ct * 16] = f2bf(v);
                    }
                } else {
                    float* orow = (float*)xtan + (size_t)row * 128 + r15;
#pragma unroll
                    for (int ct = 0; ct < 8; ++ct)
                        orow[ct * 16] = fmaf(Pr, acc[ct][reg], Qr * yb[ct]);
                }
            }
        }
    }
}

// ---------------- gather aggregate (bf16 x_tan) + fused hyp_act ----------------
__global__ __launch_bounds__(256)
void gather_act(const char* __restrict__ xt, const int* __restrict__ ptr,
                const uint2* __restrict__ epair, float* __restrict__ out, int n_rows) {
    const int v = blockIdx.x * 4 + (threadIdx.x >> 6);
    if (v >= n_rows) return;
    const int lane = threadIdx.x & 63, l2 = lane << 1;
    const unsigned loff = (unsigned)lane << 2;      // byte offset of this lane's col pair
    const int beg = ptr[v], end = ptr[v + 1];
    float a0 = 0.f, a1 = 0.f;
    int i = beg;
    for (; i + 1 < end; i += 2) {
        const uint2 p0 = epair[i], p1 = epair[i + 1];
        const unsigned u0 = *reinterpret_cast<const unsigned*>(xt + p0.x + loff);
        const unsigned u1 = *reinterpret_cast<const unsigned*>(xt + p1.x + loff);
        const float w0 = __uint_as_float(p0.y), w1 = __uint_as_float(p1.y);
        a0 = fmaf(w0, __uint_as_float(u0 << 16), a0);
        a1 = fmaf(w0, __uint_as_float(u0 & 0xffff0000u), a1);
        a0 = fmaf(w1, __uint_as_float(u1 << 16), a0);
        a1 = fmaf(w1, __uint_as_float(u1 & 0xffff0000u), a1);
    }
    if (i < end) {
        const uint2 p = epair[i];
        const unsigned u = *reinterpret_cast<const unsigned*>(xt + p.x + loff);
        const float w = __uint_as_float(p.y);
        a0 = fmaf(w, __uint_as_float(u << 16), a0);
        a1 = fmaf(w, __uint_as_float(u & 0xffff0000u), a1);
    }

    // h = proj(expmap0(agg)); xt = relu(logmap0(h)); out = proj(expmap0(xt))
    float n2 = wave_sum(a0 * a0 + a1 * a1);
    float n = fmaxf(sqrtf(n2), MIN_NORM);
    float sc = tanh_c(n) / n;
    float hn2 = sc * sc * n2;
    float f = proj_factor(hn2);
    sc *= f; hn2 *= f * f;
    float h0 = a0 * sc, h1 = a1 * sc;
    float hn = fmaxf(sqrtf(hn2), MIN_NORM);
    float sl = artanh_c(hn) / hn;
    float x0 = fmaxf(h0 * sl, 0.f), x1 = fmaxf(h1 * sl, 0.f);
    float n2b = wave_sum(x0 * x0 + x1 * x1);
    float nb = fmaxf(sqrtf(n2b), MIN_NORM);
    float scb = tanh_c(nb) / nb;
    scb *= proj_factor(scb * scb * n2b);
    *reinterpret_cast<float2*>(&out[(size_t)v * 128 + l2]) =
        make_float2(x0 * scb, x1 * scb);
}

// ---------------- fallback (atomic path, f32 x_tan) ----------------
__global__ __launch_bounds__(256)
void agg_edges(const float* __restrict__ xtan, const int* __restrict__ src,
               const int* __restrict__ dst, const float* __restrict__ ew,
               float* __restrict__ agg, int n_edges) {
    int gt = blockIdx.x * blockDim.x + threadIdx.x;
    int e = gt >> 5;
    if (e >= n_edges) return;
    int c = (gt & 31) << 2;
    int sN = src[e], dN = dst[e];
    float w = ew[e];
    const float4 v = *reinterpret_cast<const float4*>(&xtan[(size_t)sN * 128 + c]);
    float* ap = &agg[(size_t)dN * 128 + c];
    atomicAdd(ap + 0, w * v.x);
    atomicAdd(ap + 1, w * v.y);
    atomicAdd(ap + 2, w * v.z);
    atomicAdd(ap + 3, w * v.w);
}

__global__ __launch_bounds__(256)
void hyp_act_kernel(const float* __restrict__ in, float* __restrict__ out, int n_rows) {
    int row = blockIdx.x * 4 + (threadIdx.x >> 6);
    if (row >= n_rows) return;
    int lane = threadIdx.x & 63;
    int l2 = lane << 1;
    const float2 v = *reinterpret_cast<const float2*>(&in[(size_t)row * 128 + l2]);
    float a0 = v.x, a1 = v.y;
    float n2 = wave_sum(a0 * a0 + a1 * a1);
    float n = fmaxf(sqrtf(n2), MIN_NORM);
    float sc = tanh_c(n) / n;
    float hn2 = sc * sc * n2;
    float f = proj_factor(hn2);
    sc *= f; hn2 *= f * f;
    float h0 = a0 * sc, h1 = a1 * sc;
    float hn = fmaxf(sqrtf(hn2), MIN_NORM);
    float sl = artanh_c(hn) / hn;
    float x0 = fmaxf(h0 * sl, 0.f), x1 = fmaxf(h1 * sl, 0.f);
    float n2b = wave_sum(x0 * x0 + x1 * x1);
    float nb = fmaxf(sqrtf(n2b), MIN_NORM);
    float scb = tanh_c(nb) / nb;
    scb *= proj_factor(scb * scb * n2b);
    *reinterpret_cast<float2*>(&out[(size_t)row * 128 + l2]) =
        make_float2(x0 * scb, x1 * scb);
}

__global__ void bias_kernel(const float* __restrict__ b1, const float* __restrict__ b2,
                            float* __restrict__ hb1, float* __restrict__ hb2) {
    int lane = threadIdx.x;
#pragma unroll
    for (int j = 0; j < 2; ++j) {
        const float* b = j ? b2 : b1;
        float* hb = j ? hb2 : hb1;
        float v0 = b[lane], v1 = b[lane + 64];
        float n2 = wave_sum(v0 * v0 + v1 * v1);
        float n = fmaxf(sqrtf(n2), MIN_NORM);
        float sc = tanh_c(n) / n;
        sc *= proj_factor(sc * sc * n2);
        hb[lane] = v0 * sc;
        hb[lane + 64] = v1 * sc;
    }
}

__global__ void prep_w(const float* __restrict__ W1, const float* __restrict__ W2,
                       char* __restrict__ g1, char* __restrict__ g2) {
    const int b = blockIdx.x;
    const float* W = (b < 16) ? W1 : W2;
    char* out = (b < 16) ? g1 : g2;
    const int i = (((b & 15) * 256) + threadIdx.x) * 4;
    const int row = i >> 7, col = i & 127;
    const float4 w4 = *reinterpret_cast<const float4*>(&W[i]);
    ushort4 h, l;
    h.x = f2bf(w4.x); l.x = f2bf(w4.x - bf2f(h.x));
    h.y = f2bf(w4.y); l.y = f2bf(w4.y - bf2f(h.y));
    h.z = f2bf(w4.z); l.z = f2bf(w4.z - bf2f(h.z));
    h.w = f2bf(w4.w); l.w = f2bf(w4.w - bf2f(h.w));
    const unsigned byte = (unsigned)((row << 8) + (col << 1)) ^ (unsigned)((row & 7) << 4);
    *reinterpret_cast<ushort4*>(out + byte) = h;
    *reinterpret_cast<ushort4*>(out + 32768 + byte) = l;
}

extern "C" void kernel_launch(void* const* d_in, const int* in_sizes, int n_in,
                              void* d_out, int out_size, void* d_ws, size_t ws_size,
                              hipStream_t stream) {
    const float* x   = (const float*)d_in[0];
    const int*   src = (const int*)d_in[1];
    const int*   dst = (const int*)d_in[2];
    const float* ew  = (const float*)d_in[3];
    const float* W1  = (const float*)d_in[4];
    const float* b1  = (const float*)d_in[5];
    const float* W2  = (const float*)d_in[6];
    const float* b2  = (const float*)d_in[7];

    const int N = in_sizes[0] / 128;
    const int E = in_sizes[1];
    float* fout = (float*)d_out;

    const int tiles = (N + 15) >> 4;
    const int lin_blocks = (tiles + 3) / 4;
    const int nbE = (E + 255) / 256;
    const int nbN = (N + 255) / 256;

    // main-path ws: gW(128K) + xtA,xtB (bf16, N*256 B each) + epair + ints + hb
    const size_t need = 131072
                      + (size_t)N * 256 * 2
                      + (size_t)E * 8
                      + ((size_t)(N + 1) + N + N + 512) * 4
                      + 256 * 4;

    if (ws_size >= need) {
        char*  base  = (char*)d_ws;
        char*  gW1p  = base;
        char*  gW2p  = base + 65536;
        char*  xtA   = base + 131072;                 // N*128 bf16 (x_tan layer 1)
        char*  xtB   = xtA + (size_t)N * 256;         // N*128 bf16 (x_tan layer 2)
        uint2* epair = (uint2*)(xtB + (size_t)N * 256);
        int* ptr     = (int*)(epair + E);
        int* cnt     = ptr + (N + 1);
        int* cursor  = cnt + N;
        int* bsum    = cursor + N;
        int* bscan   = bsum + 256;
        float* hb1   = (float*)(bscan + 256);
        float* hb2   = hb1 + 128;

        hipMemsetAsync(cnt, 0, (size_t)N * 4, stream);
        setup_kernel<<<33 + nbE, 256, 0, stream>>>(W1, W2, gW1p, gW2p,
                                                   b1, b2, hb1, hb2, dst, cnt, E);
        scan1<<<nbN, 256, 0, stream>>>(cnt, ptr, bsum, N);
        scan2<<<1, 256, 0, stream>>>(bsum, bscan, nbN);
        scan3<<<nbN, 256, 0, stream>>>(bscan, ptr, cursor, N, E);
        scatter_kernel<<<nbE, 256, 0, stream>>>(src, dst, ew, cursor, epair, E);

        // layer 1: x -> xt1(bf16, ws) -> h1(f32, d_out)
        hyp_linear_tan_mfma<true, true><<<lin_blocks, 256, 0, stream>>>(x, gW1p, hb1, xtA, N);
        gather_act<<<(N + 3) / 4, 256, 0, stream>>>(xtA, ptr, epair, fout, N);
        // layer 2: h1(d_out) -> xt2(bf16, ws) -> final(f32, d_out; h1 dead)
        hyp_linear_tan_mfma<false, true><<<lin_blocks, 256, 0, stream>>>(fout, gW2p, hb2, xtB, N);
        gather_act<<<(N + 3) / 4, 256, 0, stream>>>(xtB, ptr, epair, fout, N);
    } else {
        // fallback: f32 atomic-scatter path
        char*  gW1p = (char*)d_ws;
        char*  gW2p = gW1p + 65536;
        float* nbuf = (float*)(gW2p + 65536);
        float* hb1  = nbuf + (size_t)N * 128;
        float* hb2  = hb1 + 128;
        const size_t node_bytes = (size_t)N * 128 * sizeof(float);
        const int agg_blocks = (int)(((size_t)E * 32 + 255) / 256);
        const int row_blocks = (N + 3) / 4;

        prep_w<<<32, 256, 0, stream>>>(W1, W2, gW1p, gW2p);
        bias_kernel<<<1, 64, 0, stream>>>(b1, b2, hb1, hb2);
        hyp_linear_tan_mfma<true, false><<<lin_blocks, 256, 0, stream>>>(x, gW1p, hb1, fout, N);
        hipMemsetAsync(nbuf, 0, node_bytes, stream);
        agg_edges<<<agg_blocks, 256, 0, stream>>>(fout, src, dst, ew, nbuf, E);
        hyp_act_kernel<<<row_blocks, 256, 0, stream>>>(nbuf, nbuf, N);
        hyp_linear_tan_mfma<false, false><<<lin_blocks, 256, 0, stream>>>(nbuf, gW2p, hb2, fout, N);
        hipMemsetAsync(fout, 0, node_bytes, stream);   // NOTE: fallback keeps R7 semantics
        agg_edges<<<agg_blocks, 256, 0, stream>>>(fout, src, dst, ew, nbuf, E);
        hyp_act_kernel<<<row_blocks, 256, 0, stream>>>(nbuf, fout, N);
    }
}